// Round 5
// baseline (1388.473 us; speedup 1.0000x reference)
//
#include <hip/hip_runtime.h>

constexpr int NN = 50000;
constexpr int EE = 800000;
constexpr int DH = 128;
constexpr int DE = 16;
constexpr int DM = 128;

typedef short bf16x8 __attribute__((ext_vector_type(8)));
typedef float f32x4 __attribute__((ext_vector_type(4)));

__device__ __forceinline__ float silu_f(float z) {
  return __fdividef(z, 1.0f + __expf(-z));
}
__device__ __forceinline__ unsigned short bf16rne(float f) {
  unsigned u = __float_as_uint(f);
  return (unsigned short)((u + 0x7FFFu + ((u >> 16) & 1u)) >> 16);
}

// --- per-node precompute: u = h @ We1[0:128,:], w = h @ We1[128:256,:] ---
__global__ __launch_bounds__(256)
void node_pre_kernel(const float* __restrict__ h, const float* __restrict__ We1,
                     float* __restrict__ u, float* __restrict__ w)
{
  __shared__ float hs[4][8 * DH];
  const int tid = threadIdx.x;
  const int lane = tid & 63;
  const int wv = tid >> 6;
  const int c0 = lane * 2;
  const int waveId = blockIdx.x * 4 + wv;
  const int nW = gridDim.x * 4;
  for (int tile = waveId; tile < NN / 8; tile += nW) {
    const long rbase = (long)tile * 8;
    const float4* hsrc = (const float4*)(h + rbase * DH);
    float4* hdst = (float4*)&hs[wv][0];
#pragma unroll
    for (int i = 0; i < 4; ++i) hdst[lane + 64 * i] = hsrc[lane + 64 * i];
    float au[8][2], aw[8][2];
#pragma unroll
    for (int r = 0; r < 8; ++r) { au[r][0] = 0.f; au[r][1] = 0.f; aw[r][0] = 0.f; aw[r][1] = 0.f; }
    for (int k = 0; k < DH; k += 4) {
      float2 a0 = *(const float2*)&We1[(k + 0) * DM + c0];
      float2 a1 = *(const float2*)&We1[(k + 1) * DM + c0];
      float2 a2 = *(const float2*)&We1[(k + 2) * DM + c0];
      float2 a3 = *(const float2*)&We1[(k + 3) * DM + c0];
      float2 b0 = *(const float2*)&We1[(DH + k + 0) * DM + c0];
      float2 b1 = *(const float2*)&We1[(DH + k + 1) * DM + c0];
      float2 b2 = *(const float2*)&We1[(DH + k + 2) * DM + c0];
      float2 b3 = *(const float2*)&We1[(DH + k + 3) * DM + c0];
#pragma unroll
      for (int r = 0; r < 8; ++r) {
        float4 hv = *(const float4*)&hs[wv][r * DH + k];
        au[r][0] += hv.x * a0.x; au[r][1] += hv.x * a0.y;
        au[r][0] += hv.y * a1.x; au[r][1] += hv.y * a1.y;
        au[r][0] += hv.z * a2.x; au[r][1] += hv.z * a2.y;
        au[r][0] += hv.w * a3.x; au[r][1] += hv.w * a3.y;
        aw[r][0] += hv.x * b0.x; aw[r][1] += hv.x * b0.y;
        aw[r][0] += hv.y * b1.x; aw[r][1] += hv.y * b1.y;
        aw[r][0] += hv.z * b2.x; aw[r][1] += hv.z * b2.y;
        aw[r][0] += hv.w * b3.x; aw[r][1] += hv.w * b3.y;
      }
    }
#pragma unroll
    for (int r = 0; r < 8; ++r) {
      *(float2*)&u[(rbase + r) * DM + c0] = make_float2(au[r][0], au[r][1]);
      *(float2*)&w[(rbase + r) * DM + c0] = make_float2(aw[r][0], aw[r][1]);
    }
  }
}

// --- dst-degree count ---
__global__ __launch_bounds__(256)
void count_kernel(const int* __restrict__ ei, float* __restrict__ cnt)
{
  int e = blockIdx.x * 256 + threadIdx.x;
  if (e < EE) atomicAdd(&cnt[ei[EE + e]], 1.0f);
}

// --- prep: Wx1 [k][n] fp32 -> WT [n][k] bf16 (global) ---
__global__ __launch_bounds__(256)
void prep_wx1t_kernel(const float* __restrict__ Wx1, unsigned short* __restrict__ WT)
{
  int i = blockIdx.x * 256 + threadIdx.x;
  if (i < DM * DM) {
    int k = i >> 7, n = i & 127;
    WT[n * DM + k] = bf16rne(Wx1[i]);
  }
}

// --- fused edge kernel: MFMA bf16, 512 thr, 2 blocks/CU, 4 waves/SIMD ---
__global__ __launch_bounds__(512, 4)
void edge_kernel(const float* __restrict__ u, const float* __restrict__ w,
                 const float* __restrict__ x, const float* __restrict__ ea,
                 const float* __restrict__ We1, const float* __restrict__ be1,
                 const float* __restrict__ We2, const float* __restrict__ be2,
                 const unsigned short* __restrict__ WT, const float* __restrict__ bx1,
                 const float* __restrict__ Wx2, const float* __restrict__ bx2,
                 const int* __restrict__ ei,
                 float* __restrict__ agg, float* __restrict__ crd)
{
  // We2 bf16, transposed [n][k], XOR-swizzled (byte ^= (n&7)<<4)
  __shared__ unsigned short We2T[DM * DM];
  // per-wave edge tile [16 edges][128 k] bf16, XOR-swizzled (byte ^= (row&7)<<4)
  __shared__ unsigned short o1s[8][16 * DM];
  __shared__ float mfs[8][64];   // sq[16], dx[16], dy[16], dz[16]
  __shared__ float eas[8][256];  // 16 edges x 16 attrs
  __shared__ int   mis[8][32];   // src[16], dst[16]

  const int tid = threadIdx.x;
  for (int idx = tid; idx < DM * DM; idx += 512) {
    int k = idx >> 7, n = idx & 127;
    int byte = (n * 256 + k * 2) ^ ((n & 7) << 4);
    *(unsigned short*)((char*)We2T + byte) = bf16rne(We2[idx]);
  }
  __syncthreads();

  const int lane = tid & 63;
  const int wv = tid >> 6;
  const int cl = lane & 15;
  const int kg = lane >> 4;       // k-group for A/B frags; row-group for C
  const int c0 = lane * 2;
  unsigned short* o1 = o1s[wv];
  float* mfw = mfs[wv];
  float* eaw = eas[wv];
  int* miw = mis[wv];

  // hoisted per-lane constants
  float wr[17][2];
#pragma unroll
  for (int t = 0; t < 17; ++t) {
    wr[t][0] = We1[(2 * DH + t) * DM + c0];
    wr[t][1] = We1[(2 * DH + t) * DM + c0 + 1];
  }
  const float be1a = be1[c0], be1b = be1[c0 + 1];
  float be2v[8], bx1v[8], wxr[8];
#pragma unroll
  for (int b = 0; b < 8; ++b) {
    be2v[b] = be2[b * 16 + cl];
    bx1v[b] = bx1[b * 16 + cl];
    wxr[b] = Wx2[b * 16 + cl];
  }
  const float bx2s = bx2[0];
  // per-lane base into WT (element offsets): row n = b*16+cl, k-base = kk*32 + kg*8
  const unsigned short* WTl = WT + cl * DM + kg * 8;

  const int waveId = blockIdx.x * 8 + wv;
  const int nW = gridDim.x * 8;

  for (int tile = waveId; tile < EE / 16; tile += nW) {
    const int e0 = tile * 16;
    if (lane < 16) {
      int s = ei[e0 + lane];
      int d = ei[EE + e0 + lane];
      miw[lane] = s;
      miw[16 + lane] = d;
      float dx = x[s * 3 + 0] - x[d * 3 + 0];
      float dy = x[s * 3 + 1] - x[d * 3 + 1];
      float dz = x[s * 3 + 2] - x[d * 3 + 2];
      mfw[lane] = dx * dx + dy * dy + dz * dz;
      mfw[16 + lane] = dx;
      mfw[32 + lane] = dy;
      mfw[48 + lane] = dz;
    }
    ((float4*)eaw)[lane] = ((const float4*)(ea + (long)e0 * DE))[lane];

    // --- layer 1 (partial-sum form) + silu -> o1 LDS (A-layout, swizzled) ---
#pragma unroll
    for (int e = 0; e < 16; ++e) {
      int s = miw[e], d = miw[16 + e];
      float2 uu = *(const float2*)&u[(long)s * DM + c0];
      float2 ww = *(const float2*)&w[(long)d * DM + c0];
      float sq = mfw[e];
      float z0 = uu.x + ww.x + be1a + sq * wr[0][0];
      float z1 = uu.y + ww.y + be1b + sq * wr[0][1];
#pragma unroll
      for (int g = 0; g < 4; ++g) {
        float4 ev = *(const float4*)&eaw[e * 16 + 4 * g];
        z0 += ev.x * wr[1 + 4 * g][0]; z1 += ev.x * wr[1 + 4 * g][1];
        z0 += ev.y * wr[2 + 4 * g][0]; z1 += ev.y * wr[2 + 4 * g][1];
        z0 += ev.z * wr[3 + 4 * g][0]; z1 += ev.z * wr[3 + 4 * g][1];
        z0 += ev.w * wr[4 + 4 * g][0]; z1 += ev.w * wr[4 + 4 * g][1];
      }
      unsigned pk = ((unsigned)bf16rne(silu_f(z1)) << 16) | bf16rne(silu_f(z0));
      int byte = (e * 256 + c0 * 2) ^ ((e & 7) << 4);
      *(unsigned*)((char*)o1 + byte) = pk;
    }

    // --- GEMM1: msg = silu(o1 @ We2 + be2); agg atomics + restore to o1 ---
    bf16x8 af[4];
#pragma unroll
    for (int kk = 0; kk < 4; ++kk) {
      int byte = (cl * 256 + kk * 64 + kg * 16) ^ ((cl & 7) << 4);
      af[kk] = *(bf16x8*)((char*)o1 + byte);
    }
    const int rbase = kg * 4;
#pragma unroll
    for (int b = 0; b < 8; ++b) {
      f32x4 acc = (f32x4){be2v[b], be2v[b], be2v[b], be2v[b]};
#pragma unroll
      for (int kk = 0; kk < 4; ++kk) {
        int byte = ((b * 16 + cl) * 256 + kk * 64 + kg * 16) ^ ((cl & 7) << 4);
        bf16x8 bfr = *(bf16x8*)((char*)We2T + byte);
        acc = __builtin_amdgcn_mfma_f32_16x16x32_bf16(af[kk], bfr, acc, 0, 0, 0);
      }
      int col = b * 16 + cl;
#pragma unroll
      for (int r = 0; r < 4; ++r) {
        int row = rbase + r;
        float m = silu_f(acc[r]);
        atomicAdd(&agg[(long)miw[16 + row] * DM + col], m);
        int byte = (row * 256 + col * 2) ^ ((row & 7) << 4);
        *(unsigned short*)((char*)o1 + byte) = bf16rne(m);
      }
    }

    // --- GEMM2: weight = silu(msg @ Wx1 + bx1) @ Wx2, B-frags from global WT ---
    bf16x8 af2[4];
#pragma unroll
    for (int kk = 0; kk < 4; ++kk) {
      int byte = (cl * 256 + kk * 64 + kg * 16) ^ ((cl & 7) << 4);
      af2[kk] = *(bf16x8*)((char*)o1 + byte);
    }
    float s0 = 0.f, s1 = 0.f, s2 = 0.f, s3 = 0.f;
#pragma unroll
    for (int b = 0; b < 8; ++b) {
      f32x4 accx = (f32x4){bx1v[b], bx1v[b], bx1v[b], bx1v[b]};
#pragma unroll
      for (int kk = 0; kk < 4; ++kk) {
        bf16x8 bfr = *(const bf16x8*)&WTl[b * 16 * DM + kk * 32];
        accx = __builtin_amdgcn_mfma_f32_16x16x32_bf16(af2[kk], bfr, accx, 0, 0, 0);
      }
      s0 += silu_f(accx[0]) * wxr[b];
      s1 += silu_f(accx[1]) * wxr[b];
      s2 += silu_f(accx[2]) * wxr[b];
      s3 += silu_f(accx[3]) * wxr[b];
    }
#pragma unroll
    for (int off = 1; off < 16; off <<= 1) {
      s0 += __shfl_xor(s0, off, 64);
      s1 += __shfl_xor(s1, off, 64);
      s2 += __shfl_xor(s2, off, 64);
      s3 += __shfl_xor(s3, off, 64);
    }

    // --- coord atomics: 12 lanes/group -> (r,c) for rows kg*4+r ---
    if (cl < 12) {
      int r = cl / 3;
      int c = cl - 3 * r;
      float sv = (r == 0) ? s0 : ((r == 1) ? s1 : ((r == 2) ? s2 : s3));
      int row = rbase + r;
      float wgt = sv + bx2s;
      int s = miw[row];
      float dcomp = mfw[16 + c * 16 + row];
      atomicAdd(&crd[(long)s * 3 + c], dcomp * wgt);
    }
  }
}

// --- node update layer 1: t = silu([h, agg/cnt] @ Wh1 + bh1) ---
__global__ __launch_bounds__(256)
void node_upd1_kernel(const float* __restrict__ h, const float* __restrict__ agg,
                      const float* __restrict__ cnt, const float* __restrict__ Wh1,
                      const float* __restrict__ bh1, float* __restrict__ t)
{
  __shared__ float hs[4][8 * DH];
  __shared__ float as_[4][8 * DM];
  const int tid = threadIdx.x;
  const int lane = tid & 63;
  const int wv = tid >> 6;
  const int c0 = lane * 2;
  const float b0 = bh1[c0], b1 = bh1[c0 + 1];
  const int waveId = blockIdx.x * 4 + wv;
  const int nW = gridDim.x * 4;
  for (int tile = waveId; tile < NN / 8; tile += nW) {
    const long rbase = (long)tile * 8;
#pragma unroll
    for (int i = 0; i < 4; ++i) {
      int f = lane + 64 * i;
      ((float4*)&hs[wv][0])[f] = ((const float4*)(h + rbase * DH))[f];
      float cv = cnt[rbase + (f >> 5)];
      float inv = __fdividef(1.0f, fmaxf(cv, 1.0f));
      float4 av = ((const float4*)(agg + rbase * DM))[f];
      av.x *= inv; av.y *= inv; av.z *= inv; av.w *= inv;
      ((float4*)&as_[wv][0])[f] = av;
    }
    float acc[8][2];
#pragma unroll
    for (int r = 0; r < 8; ++r) { acc[r][0] = b0; acc[r][1] = b1; }
    for (int k = 0; k < DH; k += 4) {
      float2 w0 = *(const float2*)&Wh1[(k + 0) * DM + c0];
      float2 w1 = *(const float2*)&Wh1[(k + 1) * DM + c0];
      float2 w2 = *(const float2*)&Wh1[(k + 2) * DM + c0];
      float2 w3 = *(const float2*)&Wh1[(k + 3) * DM + c0];
#pragma unroll
      for (int r = 0; r < 8; ++r) {
        float4 hv = *(const float4*)&hs[wv][r * DH + k];
        acc[r][0] += hv.x * w0.x; acc[r][1] += hv.x * w0.y;
        acc[r][0] += hv.y * w1.x; acc[r][1] += hv.y * w1.y;
        acc[r][0] += hv.z * w2.x; acc[r][1] += hv.z * w2.y;
        acc[r][0] += hv.w * w3.x; acc[r][1] += hv.w * w3.y;
      }
    }
    for (int k = 0; k < DM; k += 4) {
      float2 w0 = *(const float2*)&Wh1[(DH + k + 0) * DM + c0];
      float2 w1 = *(const float2*)&Wh1[(DH + k + 1) * DM + c0];
      float2 w2 = *(const float2*)&Wh1[(DH + k + 2) * DM + c0];
      float2 w3 = *(const float2*)&Wh1[(DH + k + 3) * DM + c0];
#pragma unroll
      for (int r = 0; r < 8; ++r) {
        float4 av = *(const float4*)&as_[wv][r * DM + k];
        acc[r][0] += av.x * w0.x; acc[r][1] += av.x * w0.y;
        acc[r][0] += av.y * w1.x; acc[r][1] += av.y * w1.y;
        acc[r][0] += av.z * w2.x; acc[r][1] += av.z * w2.y;
        acc[r][0] += av.w * w3.x; acc[r][1] += av.w * w3.y;
      }
    }
#pragma unroll
    for (int r = 0; r < 8; ++r)
      *(float2*)&t[(rbase + r) * DM + c0] =
          make_float2(silu_f(acc[r][0]), silu_f(acc[r][1]));
  }
}

// --- node update layer 2 + residual + layernorm ---
__global__ __launch_bounds__(256)
void node_upd2_kernel(const float* __restrict__ t, const float* __restrict__ h,
                      const float* __restrict__ Wh2, const float* __restrict__ bh2,
                      const float* __restrict__ lng, const float* __restrict__ lnb,
                      float* __restrict__ out)
{
  __shared__ float ts[4][8 * DM];
  const int tid = threadIdx.x;
  const int lane = tid & 63;
  const int wv = tid >> 6;
  const int c0 = lane * 2;
  const float b0 = bh2[c0], b1 = bh2[c0 + 1];
  const float g0 = lng[c0], g1 = lng[c0 + 1];
  const float q0 = lnb[c0], q1 = lnb[c0 + 1];
  const int waveId = blockIdx.x * 4 + wv;
  const int nW = gridDim.x * 4;
  for (int tile = waveId; tile < NN / 8; tile += nW) {
    const long rbase = (long)tile * 8;
#pragma unroll
    for (int i = 0; i < 4; ++i) {
      int f = lane + 64 * i;
      ((float4*)&ts[wv][0])[f] = ((const float4*)(t + rbase * DM))[f];
    }
    float acc[8][2];
#pragma unroll
    for (int r = 0; r < 8; ++r) { acc[r][0] = b0; acc[r][1] = b1; }
    for (int k = 0; k < DM; k += 4) {
      float2 w0 = *(const float2*)&Wh2[(k + 0) * DM + c0];
      float2 w1 = *(const float2*)&Wh2[(k + 1) * DM + c0];
      float2 w2 = *(const float2*)&Wh2[(k + 2) * DM + c0];
      float2 w3 = *(const float2*)&Wh2[(k + 3) * DM + c0];
#pragma unroll
      for (int r = 0; r < 8; ++r) {
        float4 tv = *(const float4*)&ts[wv][r * DM + k];
        acc[r][0] += tv.x * w0.x; acc[r][1] += tv.x * w0.y;
        acc[r][0] += tv.y * w1.x; acc[r][1] += tv.y * w1.y;
        acc[r][0] += tv.z * w2.x; acc[r][1] += tv.z * w2.y;
        acc[r][0] += tv.w * w3.x; acc[r][1] += tv.w * w3.y;
      }
    }
#pragma unroll
    for (int r = 0; r < 8; ++r) {
      float2 hv = *(const float2*)&h[(rbase + r) * DH + c0];
      float p0 = acc[r][0] + hv.x;
      float p1 = acc[r][1] + hv.y;
      float s = p0 + p1;
      float q = p0 * p0 + p1 * p1;
#pragma unroll
      for (int off = 32; off > 0; off >>= 1) {
        s += __shfl_xor(s, off, 64);
        q += __shfl_xor(q, off, 64);
      }
      float mean = s * (1.0f / 128.0f);
      float var = q * (1.0f / 128.0f) - mean * mean;
      float rs = rsqrtf(var + 1e-5f);
      float y0 = (p0 - mean) * rs * g0 + q0;
      float y1 = (p1 - mean) * rs * g1 + q1;
      *(float2*)&out[(rbase + r) * DM + c0] = make_float2(y0, y1);
    }
  }
}

// --- x output ---
__global__ __launch_bounds__(256)
void xout_kernel(const float* __restrict__ x, const float* __restrict__ crd,
                 const float* __restrict__ cnt, float* __restrict__ out)
{
  int i = blockIdx.x * 256 + threadIdx.x;
  if (i < NN * 3) {
    int n = i / 3;
    float cv = fmaxf(cnt[n], 1.0f);
    out[i] = x[i] + crd[i] * __fdividef(1.0f, cv);
  }
}

extern "C" void kernel_launch(void* const* d_in, const int* in_sizes, int n_in,
                              void* d_out, int out_size, void* d_ws, size_t ws_size,
                              hipStream_t stream)
{
  (void)in_sizes; (void)n_in; (void)out_size; (void)ws_size;
  const float* h   = (const float*)d_in[0];
  const float* x   = (const float*)d_in[1];
  const float* ea  = (const float*)d_in[2];
  const float* We1 = (const float*)d_in[3];
  const float* be1 = (const float*)d_in[4];
  const float* We2 = (const float*)d_in[5];
  const float* be2 = (const float*)d_in[6];
  const float* Wh1 = (const float*)d_in[7];
  const float* bh1 = (const float*)d_in[8];
  const float* Wh2 = (const float*)d_in[9];
  const float* bh2 = (const float*)d_in[10];
  const float* Wx1 = (const float*)d_in[11];
  const float* bx1 = (const float*)d_in[12];
  const float* Wx2 = (const float*)d_in[13];
  const float* bx2 = (const float*)d_in[14];
  const float* lng = (const float*)d_in[15];
  const float* lnb = (const float*)d_in[16];
  const int*   ei  = (const int*)d_in[17];
  float* out = (float*)d_out;
  float* ws  = (float*)d_ws;

  float* u   = ws;                 // N*128
  float* w   = ws + 6400000;       // N*128
  float* agg = ws + 12800000;      // N*128
  float* cnt = ws + 19200000;      // N
  float* crd = ws + 19250000;      // N*3
  unsigned short* WT = (unsigned short*)(ws + 19400000);  // 128*128 bf16
  float* t   = u;                  // reuse u after edge kernel

  hipMemsetAsync(agg, 0, (6400000 + 50000 + 150000) * sizeof(float), stream);

  node_pre_kernel<<<1563, 256, 0, stream>>>(h, We1, u, w);
  count_kernel<<<(EE + 255) / 256, 256, 0, stream>>>(ei, cnt);
  prep_wx1t_kernel<<<64, 256, 0, stream>>>(Wx1, WT);
  edge_kernel<<<512, 512, 0, stream>>>(u, w, x, ea, We1, be1, We2, be2,
                                       WT, bx1, Wx2, bx2, ei, agg, crd);
  node_upd1_kernel<<<1563, 256, 0, stream>>>(h, agg, cnt, Wh1, bh1, t);
  node_upd2_kernel<<<1563, 256, 0, stream>>>(t, h, Wh2, bh2, lng, lnb, out);
  xout_kernel<<<(NN * 3 + 255) / 256, 256, 0, stream>>>(x, crd, cnt, out + 6400000);
}

// Round 6
// 1220.777 us; speedup vs baseline: 1.1374x; 1.1374x over previous
//
#include <hip/hip_runtime.h>

constexpr int NN = 50000;
constexpr int EE = 800000;
constexpr int DH = 128;
constexpr int DE = 16;
constexpr int DM = 128;

typedef short bf16x8 __attribute__((ext_vector_type(8)));
typedef float f32x4 __attribute__((ext_vector_type(4)));

__device__ __forceinline__ float silu_f(float z) {
  return __fdividef(z, 1.0f + __expf(-z));
}
__device__ __forceinline__ unsigned short bf16rne(float f) {
  unsigned u = __float_as_uint(f);
  return (unsigned short)((u + 0x7FFFu + ((u >> 16) & 1u)) >> 16);
}

// --- per-node precompute: u = h @ We1[0:128,:], w = h @ We1[128:256,:] ---
__global__ __launch_bounds__(256)
void node_pre_kernel(const float* __restrict__ h, const float* __restrict__ We1,
                     float* __restrict__ u, float* __restrict__ w)
{
  __shared__ float hs[4][8 * DH];
  const int tid = threadIdx.x;
  const int lane = tid & 63;
  const int wv = tid >> 6;
  const int c0 = lane * 2;
  const int waveId = blockIdx.x * 4 + wv;
  const int nW = gridDim.x * 4;
  for (int tile = waveId; tile < NN / 8; tile += nW) {
    const long rbase = (long)tile * 8;
    const float4* hsrc = (const float4*)(h + rbase * DH);
    float4* hdst = (float4*)&hs[wv][0];
#pragma unroll
    for (int i = 0; i < 4; ++i) hdst[lane + 64 * i] = hsrc[lane + 64 * i];
    float au[8][2], aw[8][2];
#pragma unroll
    for (int r = 0; r < 8; ++r) { au[r][0] = 0.f; au[r][1] = 0.f; aw[r][0] = 0.f; aw[r][1] = 0.f; }
    for (int k = 0; k < DH; k += 4) {
      float2 a0 = *(const float2*)&We1[(k + 0) * DM + c0];
      float2 a1 = *(const float2*)&We1[(k + 1) * DM + c0];
      float2 a2 = *(const float2*)&We1[(k + 2) * DM + c0];
      float2 a3 = *(const float2*)&We1[(k + 3) * DM + c0];
      float2 b0 = *(const float2*)&We1[(DH + k + 0) * DM + c0];
      float2 b1 = *(const float2*)&We1[(DH + k + 1) * DM + c0];
      float2 b2 = *(const float2*)&We1[(DH + k + 2) * DM + c0];
      float2 b3 = *(const float2*)&We1[(DH + k + 3) * DM + c0];
#pragma unroll
      for (int r = 0; r < 8; ++r) {
        float4 hv = *(const float4*)&hs[wv][r * DH + k];
        au[r][0] += hv.x * a0.x; au[r][1] += hv.x * a0.y;
        au[r][0] += hv.y * a1.x; au[r][1] += hv.y * a1.y;
        au[r][0] += hv.z * a2.x; au[r][1] += hv.z * a2.y;
        au[r][0] += hv.w * a3.x; au[r][1] += hv.w * a3.y;
        aw[r][0] += hv.x * b0.x; aw[r][1] += hv.x * b0.y;
        aw[r][0] += hv.y * b1.x; aw[r][1] += hv.y * b1.y;
        aw[r][0] += hv.z * b2.x; aw[r][1] += hv.z * b2.y;
        aw[r][0] += hv.w * b3.x; aw[r][1] += hv.w * b3.y;
      }
    }
#pragma unroll
    for (int r = 0; r < 8; ++r) {
      *(float2*)&u[(rbase + r) * DM + c0] = make_float2(au[r][0], au[r][1]);
      *(float2*)&w[(rbase + r) * DM + c0] = make_float2(aw[r][0], aw[r][1]);
    }
  }
}

// --- dst-degree count ---
__global__ __launch_bounds__(256)
void count_kernel(const int* __restrict__ ei, float* __restrict__ cnt)
{
  int e = blockIdx.x * 256 + threadIdx.x;
  if (e < EE) atomicAdd(&cnt[ei[EE + e]], 1.0f);
}

// --- prep: Wx1 [k][n] fp32 -> WT [n][k] bf16 (global) ---
__global__ __launch_bounds__(256)
void prep_wx1t_kernel(const float* __restrict__ Wx1, unsigned short* __restrict__ WT)
{
  int i = blockIdx.x * 256 + threadIdx.x;
  if (i < DM * DM) {
    int k = i >> 7, n = i & 127;
    WT[n * DM + k] = bf16rne(Wx1[i]);
  }
}

// --- fused edge kernel: MFMA bf16, 512 thr, We2 in LDS, Wx1T global ---
__global__ __launch_bounds__(512, 2)
void edge_kernel(const float* __restrict__ u, const float* __restrict__ w,
                 const float* __restrict__ x, const float* __restrict__ ea,
                 const float* __restrict__ We1, const float* __restrict__ be1,
                 const float* __restrict__ We2, const float* __restrict__ be2,
                 const unsigned short* __restrict__ WT, const float* __restrict__ bx1,
                 const float* __restrict__ Wx2, const float* __restrict__ bx2,
                 const int* __restrict__ ei,
                 float* __restrict__ agg, float* __restrict__ crd)
{
  // We2 bf16, transposed [n][k], XOR-swizzled (byte ^= (n&7)<<4)
  __shared__ unsigned short We2T[DM * DM];
  // per-wave edge tile [16 edges][128 k] bf16, XOR-swizzled (byte ^= (row&7)<<4)
  __shared__ unsigned short o1s[8][16 * DM];
  __shared__ float mfs[8][64];   // sq[16], dx[16], dy[16], dz[16]
  __shared__ float eas[8][256];  // 16 edges x 16 attrs
  __shared__ int   mis[8][32];   // src[16], dst[16]

  const int tid = threadIdx.x;
  for (int idx = tid; idx < DM * DM; idx += 512) {
    int k = idx >> 7, n = idx & 127;
    int byte = (n * 256 + k * 2) ^ ((n & 7) << 4);
    *(unsigned short*)((char*)We2T + byte) = bf16rne(We2[idx]);
  }
  __syncthreads();

  const int lane = tid & 63;
  const int wv = tid >> 6;
  const int cl = lane & 15;
  const int kg = lane >> 4;       // k-group for A/B frags; row-group for C
  const int c0 = lane * 2;
  unsigned short* o1 = o1s[wv];
  float* mfw = mfs[wv];
  float* eaw = eas[wv];
  int* miw = mis[wv];

  // hoisted per-lane constants
  float wr[17][2];
#pragma unroll
  for (int t = 0; t < 17; ++t) {
    wr[t][0] = We1[(2 * DH + t) * DM + c0];
    wr[t][1] = We1[(2 * DH + t) * DM + c0 + 1];
  }
  const float be1a = be1[c0], be1b = be1[c0 + 1];
  float be2v[8], bx1v[8], wxr[8];
#pragma unroll
  for (int b = 0; b < 8; ++b) {
    be2v[b] = be2[b * 16 + cl];
    bx1v[b] = bx1[b * 16 + cl];
    wxr[b] = Wx2[b * 16 + cl];
  }
  const float bx2s = bx2[0];
  // per-lane base into WT (element offsets): row n = b*16+cl, k = kk*32 + kg*8
  const unsigned short* WTl = WT + cl * DM + kg * 8;

  const int waveId = blockIdx.x * 8 + wv;
  const int nW = gridDim.x * 8;

  for (int tile = waveId; tile < EE / 16; tile += nW) {
    const int e0 = tile * 16;
    if (lane < 16) {
      int s = ei[e0 + lane];
      int d = ei[EE + e0 + lane];
      miw[lane] = s;
      miw[16 + lane] = d;
      float dx = x[s * 3 + 0] - x[d * 3 + 0];
      float dy = x[s * 3 + 1] - x[d * 3 + 1];
      float dz = x[s * 3 + 2] - x[d * 3 + 2];
      mfw[lane] = dx * dx + dy * dy + dz * dz;
      mfw[16 + lane] = dx;
      mfw[32 + lane] = dy;
      mfw[48 + lane] = dz;
    }
    ((float4*)eaw)[lane] = ((const float4*)(ea + (long)e0 * DE))[lane];

    // --- layer 1 (partial-sum form) + silu -> o1 LDS (A-layout, swizzled) ---
#pragma unroll
    for (int e = 0; e < 16; ++e) {
      int s = miw[e], d = miw[16 + e];
      float2 uu = *(const float2*)&u[(long)s * DM + c0];
      float2 ww = *(const float2*)&w[(long)d * DM + c0];
      float sq = mfw[e];
      float z0 = uu.x + ww.x + be1a + sq * wr[0][0];
      float z1 = uu.y + ww.y + be1b + sq * wr[0][1];
#pragma unroll
      for (int g = 0; g < 4; ++g) {
        float4 ev = *(const float4*)&eaw[e * 16 + 4 * g];
        z0 += ev.x * wr[1 + 4 * g][0]; z1 += ev.x * wr[1 + 4 * g][1];
        z0 += ev.y * wr[2 + 4 * g][0]; z1 += ev.y * wr[2 + 4 * g][1];
        z0 += ev.z * wr[3 + 4 * g][0]; z1 += ev.z * wr[3 + 4 * g][1];
        z0 += ev.w * wr[4 + 4 * g][0]; z1 += ev.w * wr[4 + 4 * g][1];
      }
      unsigned pk = ((unsigned)bf16rne(silu_f(z1)) << 16) | bf16rne(silu_f(z0));
      int byte = (e * 256 + c0 * 2) ^ ((e & 7) << 4);
      *(unsigned*)((char*)o1 + byte) = pk;
    }

    // --- GEMM1: msg_pre = o1 @ We2 + be2 (batch accumulators) ---
    bf16x8 af[4];
#pragma unroll
    for (int kk = 0; kk < 4; ++kk) {
      int byte = (cl * 256 + kk * 64 + kg * 16) ^ ((cl & 7) << 4);
      af[kk] = *(bf16x8*)((char*)o1 + byte);
    }
    f32x4 acc[8];
#pragma unroll
    for (int b = 0; b < 8; ++b) {
      acc[b] = (f32x4){be2v[b], be2v[b], be2v[b], be2v[b]};
#pragma unroll
      for (int kk = 0; kk < 4; ++kk) {
        int byte = ((b * 16 + cl) * 256 + kk * 64 + kg * 16) ^ ((cl & 7) << 4);
        bf16x8 bfr = *(bf16x8*)((char*)We2T + byte);
        acc[b] = __builtin_amdgcn_mfma_f32_16x16x32_bf16(af[kk], bfr, acc[b], 0, 0, 0);
      }
    }

    // --- msg = silu -> agg atomics (fp32) + restore to o1 (A-layout bf16) ---
    const int rbase = kg * 4;
#pragma unroll
    for (int b = 0; b < 8; ++b) {
      int col = b * 16 + cl;
#pragma unroll
      for (int r = 0; r < 4; ++r) {
        int row = rbase + r;
        float m = silu_f(acc[b][r]);
        atomicAdd(&agg[(long)miw[16 + row] * DM + col], m);
        int byte = (row * 256 + col * 2) ^ ((row & 7) << 4);
        *(unsigned short*)((char*)o1 + byte) = bf16rne(m);
      }
    }

    // --- GEMM2: xh = msg @ Wx1 + bx1, B-frags from global WT ---
    bf16x8 af2[4];
#pragma unroll
    for (int kk = 0; kk < 4; ++kk) {
      int byte = (cl * 256 + kk * 64 + kg * 16) ^ ((cl & 7) << 4);
      af2[kk] = *(bf16x8*)((char*)o1 + byte);
    }
    f32x4 accx[8];
#pragma unroll
    for (int b = 0; b < 8; ++b) {
      accx[b] = (f32x4){bx1v[b], bx1v[b], bx1v[b], bx1v[b]};
#pragma unroll
      for (int kk = 0; kk < 4; ++kk) {
        bf16x8 bfr = *(const bf16x8*)&WTl[b * 16 * DM + kk * 32];
        accx[b] = __builtin_amdgcn_mfma_f32_16x16x32_bf16(af2[kk], bfr, accx[b], 0, 0, 0);
      }
    }

    // --- weight = silu(xh) @ Wx2 + bx2, reduce over cols ---
    float s0 = 0.f, s1 = 0.f, s2 = 0.f, s3 = 0.f;
#pragma unroll
    for (int b = 0; b < 8; ++b) {
      s0 += silu_f(accx[b][0]) * wxr[b];
      s1 += silu_f(accx[b][1]) * wxr[b];
      s2 += silu_f(accx[b][2]) * wxr[b];
      s3 += silu_f(accx[b][3]) * wxr[b];
    }
#pragma unroll
    for (int off = 1; off < 16; off <<= 1) {
      s0 += __shfl_xor(s0, off, 64);
      s1 += __shfl_xor(s1, off, 64);
      s2 += __shfl_xor(s2, off, 64);
      s3 += __shfl_xor(s3, off, 64);
    }

    // --- coord atomics: 12 lanes/group -> (r,c) for rows kg*4+r ---
    if (cl < 12) {
      int r = cl / 3;
      int c = cl - 3 * r;
      float sv = (r == 0) ? s0 : ((r == 1) ? s1 : ((r == 2) ? s2 : s3));
      int row = rbase + r;
      float wgt = sv + bx2s;
      int s = miw[row];
      float dcomp = mfw[16 + c * 16 + row];
      atomicAdd(&crd[(long)s * 3 + c], dcomp * wgt);
    }
  }
}

// --- node update layer 1: t = silu([h, agg/cnt] @ Wh1 + bh1) ---
__global__ __launch_bounds__(256)
void node_upd1_kernel(const float* __restrict__ h, const float* __restrict__ agg,
                      const float* __restrict__ cnt, const float* __restrict__ Wh1,
                      const float* __restrict__ bh1, float* __restrict__ t)
{
  __shared__ float hs[4][8 * DH];
  __shared__ float as_[4][8 * DM];
  const int tid = threadIdx.x;
  const int lane = tid & 63;
  const int wv = tid >> 6;
  const int c0 = lane * 2;
  const float b0 = bh1[c0], b1 = bh1[c0 + 1];
  const int waveId = blockIdx.x * 4 + wv;
  const int nW = gridDim.x * 4;
  for (int tile = waveId; tile < NN / 8; tile += nW) {
    const long rbase = (long)tile * 8;
#pragma unroll
    for (int i = 0; i < 4; ++i) {
      int f = lane + 64 * i;
      ((float4*)&hs[wv][0])[f] = ((const float4*)(h + rbase * DH))[f];
      float cv = cnt[rbase + (f >> 5)];
      float inv = __fdividef(1.0f, fmaxf(cv, 1.0f));
      float4 av = ((const float4*)(agg + rbase * DM))[f];
      av.x *= inv; av.y *= inv; av.z *= inv; av.w *= inv;
      ((float4*)&as_[wv][0])[f] = av;
    }
    float acc[8][2];
#pragma unroll
    for (int r = 0; r < 8; ++r) { acc[r][0] = b0; acc[r][1] = b1; }
    for (int k = 0; k < DH; k += 4) {
      float2 w0 = *(const float2*)&Wh1[(k + 0) * DM + c0];
      float2 w1 = *(const float2*)&Wh1[(k + 1) * DM + c0];
      float2 w2 = *(const float2*)&Wh1[(k + 2) * DM + c0];
      float2 w3 = *(const float2*)&Wh1[(k + 3) * DM + c0];
#pragma unroll
      for (int r = 0; r < 8; ++r) {
        float4 hv = *(const float4*)&hs[wv][r * DH + k];
        acc[r][0] += hv.x * w0.x; acc[r][1] += hv.x * w0.y;
        acc[r][0] += hv.y * w1.x; acc[r][1] += hv.y * w1.y;
        acc[r][0] += hv.z * w2.x; acc[r][1] += hv.z * w2.y;
        acc[r][0] += hv.w * w3.x; acc[r][1] += hv.w * w3.y;
      }
    }
    for (int k = 0; k < DM; k += 4) {
      float2 w0 = *(const float2*)&Wh1[(DH + k + 0) * DM + c0];
      float2 w1 = *(const float2*)&Wh1[(DH + k + 1) * DM + c0];
      float2 w2 = *(const float2*)&Wh1[(DH + k + 2) * DM + c0];
      float2 w3 = *(const float2*)&Wh1[(DH + k + 3) * DM + c0];
#pragma unroll
      for (int r = 0; r < 8; ++r) {
        float4 av = *(const float4*)&as_[wv][r * DM + k];
        acc[r][0] += av.x * w0.x; acc[r][1] += av.x * w0.y;
        acc[r][0] += av.y * w1.x; acc[r][1] += av.y * w1.y;
        acc[r][0] += av.z * w2.x; acc[r][1] += av.z * w2.y;
        acc[r][0] += av.w * w3.x; acc[r][1] += av.w * w3.y;
      }
    }
#pragma unroll
    for (int r = 0; r < 8; ++r)
      *(float2*)&t[(rbase + r) * DM + c0] =
          make_float2(silu_f(acc[r][0]), silu_f(acc[r][1]));
  }
}

// --- node update layer 2 + residual + layernorm ---
__global__ __launch_bounds__(256)
void node_upd2_kernel(const float* __restrict__ t, const float* __restrict__ h,
                      const float* __restrict__ Wh2, const float* __restrict__ bh2,
                      const float* __restrict__ lng, const float* __restrict__ lnb,
                      float* __restrict__ out)
{
  __shared__ float ts[4][8 * DM];
  const int tid = threadIdx.x;
  const int lane = tid & 63;
  const int wv = tid >> 6;
  const int c0 = lane * 2;
  const float b0 = bh2[c0], b1 = bh2[c0 + 1];
  const float g0 = lng[c0], g1 = lng[c0 + 1];
  const float q0 = lnb[c0], q1 = lnb[c0 + 1];
  const int waveId = blockIdx.x * 4 + wv;
  const int nW = gridDim.x * 4;
  for (int tile = waveId; tile < NN / 8; tile += nW) {
    const long rbase = (long)tile * 8;
#pragma unroll
    for (int i = 0; i < 4; ++i) {
      int f = lane + 64 * i;
      ((float4*)&ts[wv][0])[f] = ((const float4*)(t + rbase * DM))[f];
    }
    float acc[8][2];
#pragma unroll
    for (int r = 0; r < 8; ++r) { acc[r][0] = b0; acc[r][1] = b1; }
    for (int k = 0; k < DM; k += 4) {
      float2 w0 = *(const float2*)&Wh2[(k + 0) * DM + c0];
      float2 w1 = *(const float2*)&Wh2[(k + 1) * DM + c0];
      float2 w2 = *(const float2*)&Wh2[(k + 2) * DM + c0];
      float2 w3 = *(const float2*)&Wh2[(k + 3) * DM + c0];
#pragma unroll
      for (int r = 0; r < 8; ++r) {
        float4 tv = *(const float4*)&ts[wv][r * DM + k];
        acc[r][0] += tv.x * w0.x; acc[r][1] += tv.x * w0.y;
        acc[r][0] += tv.y * w1.x; acc[r][1] += tv.y * w1.y;
        acc[r][0] += tv.z * w2.x; acc[r][1] += tv.z * w2.y;
        acc[r][0] += tv.w * w3.x; acc[r][1] += tv.w * w3.y;
      }
    }
#pragma unroll
    for (int r = 0; r < 8; ++r) {
      float2 hv = *(const float2*)&h[(rbase + r) * DH + c0];
      float p0 = acc[r][0] + hv.x;
      float p1 = acc[r][1] + hv.y;
      float s = p0 + p1;
      float q = p0 * p0 + p1 * p1;
#pragma unroll
      for (int off = 32; off > 0; off >>= 1) {
        s += __shfl_xor(s, off, 64);
        q += __shfl_xor(q, off, 64);
      }
      float mean = s * (1.0f / 128.0f);
      float var = q * (1.0f / 128.0f) - mean * mean;
      float rs = rsqrtf(var + 1e-5f);
      float y0 = (p0 - mean) * rs * g0 + q0;
      float y1 = (p1 - mean) * rs * g1 + q1;
      *(float2*)&out[(rbase + r) * DM + c0] = make_float2(y0, y1);
    }
  }
}

// --- x output ---
__global__ __launch_bounds__(256)
void xout_kernel(const float* __restrict__ x, const float* __restrict__ crd,
                 const float* __restrict__ cnt, float* __restrict__ out)
{
  int i = blockIdx.x * 256 + threadIdx.x;
  if (i < NN * 3) {
    int n = i / 3;
    float cv = fmaxf(cnt[n], 1.0f);
    out[i] = x[i] + crd[i] * __fdividef(1.0f, cv);
  }
}

extern "C" void kernel_launch(void* const* d_in, const int* in_sizes, int n_in,
                              void* d_out, int out_size, void* d_ws, size_t ws_size,
                              hipStream_t stream)
{
  (void)in_sizes; (void)n_in; (void)out_size; (void)ws_size;
  const float* h   = (const float*)d_in[0];
  const float* x   = (const float*)d_in[1];
  const float* ea  = (const float*)d_in[2];
  const float* We1 = (const float*)d_in[3];
  const float* be1 = (const float*)d_in[4];
  const float* We2 = (const float*)d_in[5];
  const float* be2 = (const float*)d_in[6];
  const float* Wh1 = (const float*)d_in[7];
  const float* bh1 = (const float*)d_in[8];
  const float* Wh2 = (const float*)d_in[9];
  const float* bh2 = (const float*)d_in[10];
  const float* Wx1 = (const float*)d_in[11];
  const float* bx1 = (const float*)d_in[12];
  const float* Wx2 = (const float*)d_in[13];
  const float* bx2 = (const float*)d_in[14];
  const float* lng = (const float*)d_in[15];
  const float* lnb = (const float*)d_in[16];
  const int*   ei  = (const int*)d_in[17];
  float* out = (float*)d_out;
  float* ws  = (float*)d_ws;

  float* u   = ws;                 // N*128
  float* w   = ws + 6400000;       // N*128
  float* agg = ws + 12800000;      // N*128
  float* cnt = ws + 19200000;      // N
  float* crd = ws + 19250000;      // N*3
  unsigned short* WT = (unsigned short*)(ws + 19400000);  // 128*128 bf16
  float* t   = u;                  // reuse u after edge kernel

  hipMemsetAsync(agg, 0, (6400000 + 50000 + 150000) * sizeof(float), stream);

  node_pre_kernel<<<1563, 256, 0, stream>>>(h, We1, u, w);
  count_kernel<<<(EE + 255) / 256, 256, 0, stream>>>(ei, cnt);
  prep_wx1t_kernel<<<64, 256, 0, stream>>>(Wx1, WT);
  edge_kernel<<<512, 512, 0, stream>>>(u, w, x, ea, We1, be1, We2, be2,
                                       WT, bx1, Wx2, bx2, ei, agg, crd);
  node_upd1_kernel<<<1563, 256, 0, stream>>>(h, agg, cnt, Wh1, bh1, t);
  node_upd2_kernel<<<1563, 256, 0, stream>>>(t, h, Wh2, bh2, lng, lnb, out);
  xout_kernel<<<(NN * 3 + 255) / 256, 256, 0, stream>>>(x, crd, cnt, out + 6400000);
}

// Round 7
// 898.195 us; speedup vs baseline: 1.5458x; 1.3591x over previous
//
#include <hip/hip_runtime.h>

constexpr int NN = 50000;
constexpr int EE = 800000;
constexpr int DH = 128;
constexpr int DE = 16;
constexpr int DM = 128;

typedef short bf16x8 __attribute__((ext_vector_type(8)));
typedef float f32x4 __attribute__((ext_vector_type(4)));

__device__ __forceinline__ float silu_f(float z) {
  return __fdividef(z, 1.0f + __expf(-z));
}
__device__ __forceinline__ unsigned short bf16rne(float f) {
  unsigned u = __float_as_uint(f);
  return (unsigned short)((u + 0x7FFFu + ((u >> 16) & 1u)) >> 16);
}

// --- per-node precompute: u = h @ We1[0:128,:], w = h @ We1[128:256,:] ---
__global__ __launch_bounds__(256)
void node_pre_kernel(const float* __restrict__ h, const float* __restrict__ We1,
                     float* __restrict__ u, float* __restrict__ w)
{
  __shared__ float hs[4][8 * DH];
  const int tid = threadIdx.x;
  const int lane = tid & 63;
  const int wv = tid >> 6;
  const int c0 = lane * 2;
  const int waveId = blockIdx.x * 4 + wv;
  const int nW = gridDim.x * 4;
  for (int tile = waveId; tile < NN / 8; tile += nW) {
    const long rbase = (long)tile * 8;
    const float4* hsrc = (const float4*)(h + rbase * DH);
    float4* hdst = (float4*)&hs[wv][0];
#pragma unroll
    for (int i = 0; i < 4; ++i) hdst[lane + 64 * i] = hsrc[lane + 64 * i];
    float au[8][2], aw[8][2];
#pragma unroll
    for (int r = 0; r < 8; ++r) { au[r][0] = 0.f; au[r][1] = 0.f; aw[r][0] = 0.f; aw[r][1] = 0.f; }
    for (int k = 0; k < DH; k += 4) {
      float2 a0 = *(const float2*)&We1[(k + 0) * DM + c0];
      float2 a1 = *(const float2*)&We1[(k + 1) * DM + c0];
      float2 a2 = *(const float2*)&We1[(k + 2) * DM + c0];
      float2 a3 = *(const float2*)&We1[(k + 3) * DM + c0];
      float2 b0 = *(const float2*)&We1[(DH + k + 0) * DM + c0];
      float2 b1 = *(const float2*)&We1[(DH + k + 1) * DM + c0];
      float2 b2 = *(const float2*)&We1[(DH + k + 2) * DM + c0];
      float2 b3 = *(const float2*)&We1[(DH + k + 3) * DM + c0];
#pragma unroll
      for (int r = 0; r < 8; ++r) {
        float4 hv = *(const float4*)&hs[wv][r * DH + k];
        au[r][0] += hv.x * a0.x; au[r][1] += hv.x * a0.y;
        au[r][0] += hv.y * a1.x; au[r][1] += hv.y * a1.y;
        au[r][0] += hv.z * a2.x; au[r][1] += hv.z * a2.y;
        au[r][0] += hv.w * a3.x; au[r][1] += hv.w * a3.y;
        aw[r][0] += hv.x * b0.x; aw[r][1] += hv.x * b0.y;
        aw[r][0] += hv.y * b1.x; aw[r][1] += hv.y * b1.y;
        aw[r][0] += hv.z * b2.x; aw[r][1] += hv.z * b2.y;
        aw[r][0] += hv.w * b3.x; aw[r][1] += hv.w * b3.y;
      }
    }
#pragma unroll
    for (int r = 0; r < 8; ++r) {
      *(float2*)&u[(rbase + r) * DM + c0] = make_float2(au[r][0], au[r][1]);
      *(float2*)&w[(rbase + r) * DM + c0] = make_float2(aw[r][0], aw[r][1]);
    }
  }
}

// --- dst-degree count ---
__global__ __launch_bounds__(256)
void count_kernel(const int* __restrict__ ei, float* __restrict__ cnt)
{
  int e = blockIdx.x * 256 + threadIdx.x;
  if (e < EE) atomicAdd(&cnt[ei[EE + e]], 1.0f);
}

// --- fused edge kernel: MFMA bf16, software-pipelined tile loop ---
__global__ __launch_bounds__(512, 1)
void edge_kernel(const float* __restrict__ u, const float* __restrict__ w,
                 const float* __restrict__ x, const float* __restrict__ ea,
                 const float* __restrict__ We1, const float* __restrict__ be1,
                 const float* __restrict__ We2, const float* __restrict__ be2,
                 const float* __restrict__ Wx1, const float* __restrict__ bx1,
                 const float* __restrict__ Wx2, const float* __restrict__ bx2,
                 const int* __restrict__ ei,
                 float* __restrict__ agg, float* __restrict__ crd)
{
  // weights bf16, transposed [n][k], XOR-swizzled (byte ^= (n&7)<<4)
  __shared__ unsigned short We2T[DM * DM];
  __shared__ unsigned short Wx1T[DM * DM];
  // per-wave edge tile [16 edges][128 k] bf16, XOR-swizzled (byte ^= (row&7)<<4)
  __shared__ unsigned short o1s[8][16 * DM];
  // double-buffered per-wave metadata
  __shared__ float mfs[8][2][64];   // sq[16], dx[16], dy[16], dz[16]
  __shared__ float eas[8][2][256];  // 16 edges x 16 attrs
  __shared__ int   mis[8][2][32];   // src[16], dst[16]

  const int tid = threadIdx.x;
  for (int idx = tid; idx < DM * DM; idx += 512) {
    int k = idx >> 7, n = idx & 127;
    int byte = (n * 256 + k * 2) ^ ((n & 7) << 4);
    *(unsigned short*)((char*)We2T + byte) = bf16rne(We2[idx]);
    *(unsigned short*)((char*)Wx1T + byte) = bf16rne(Wx1[idx]);
  }
  __syncthreads();

  const int lane = tid & 63;
  const int wv = tid >> 6;
  const int cl = lane & 15;
  const int kg = lane >> 4;       // k-group for A/B frags; row-group for C
  const int c0 = lane * 2;
  unsigned short* o1 = o1s[wv];

  // hoisted per-lane constants
  float wr[17][2];
#pragma unroll
  for (int t = 0; t < 17; ++t) {
    wr[t][0] = We1[(2 * DH + t) * DM + c0];
    wr[t][1] = We1[(2 * DH + t) * DM + c0 + 1];
  }
  const float be1a = be1[c0], be1b = be1[c0 + 1];
  float be2v[8], bx1v[8], wxr[8];
#pragma unroll
  for (int b = 0; b < 8; ++b) {
    be2v[b] = be2[b * 16 + cl];
    bx1v[b] = bx1[b * 16 + cl];
    wxr[b] = Wx2[b * 16 + cl];
  }
  const float bx2s = bx2[0];

  auto load_meta = [&](int tt, int buf) {
    const int e0 = tt * 16;
    if (lane < 16) {
      int s = ei[e0 + lane];
      int d = ei[EE + e0 + lane];
      mis[wv][buf][lane] = s;
      mis[wv][buf][16 + lane] = d;
      float dx = x[s * 3 + 0] - x[d * 3 + 0];
      float dy = x[s * 3 + 1] - x[d * 3 + 1];
      float dz = x[s * 3 + 2] - x[d * 3 + 2];
      mfs[wv][buf][lane] = dx * dx + dy * dy + dz * dz;
      mfs[wv][buf][16 + lane] = dx;
      mfs[wv][buf][32 + lane] = dy;
      mfs[wv][buf][48 + lane] = dz;
    }
    ((float4*)&eas[wv][buf][0])[lane] = ((const float4*)(ea + (long)e0 * DE))[lane];
  };

  const int waveId = blockIdx.x * 8 + wv;
  const int nW = gridDim.x * 8;
  constexpr int NT = EE / 16;

  int cur = 0;
  float2 uu[16], ww[16];
  // prologue: meta + gathers for first tile
  if (waveId < NT) {
    load_meta(waveId, 0);
#pragma unroll
    for (int e = 0; e < 16; ++e) {
      int s = mis[wv][0][e];
      int d = mis[wv][0][16 + e];
      uu[e] = *(const float2*)&u[(long)s * DM + c0];
      ww[e] = *(const float2*)&w[(long)d * DM + c0];
    }
  }

  for (int tile = waveId; tile < NT; tile += nW) {
    const int nxt = tile + nW;
    const int nb = cur ^ 1;
    const float* mfw = &mfs[wv][cur][0];
    const float* eaw = &eas[wv][cur][0];
    const int* miw = &mis[wv][cur][0];

    // --- layer 1 (partial-sum form, reg-resident gathers) + silu -> o1 ---
#pragma unroll
    for (int e = 0; e < 16; ++e) {
      float sq = mfw[e];
      float z0 = uu[e].x + ww[e].x + be1a + sq * wr[0][0];
      float z1 = uu[e].y + ww[e].y + be1b + sq * wr[0][1];
#pragma unroll
      for (int g = 0; g < 4; ++g) {
        float4 ev = *(const float4*)&eaw[e * 16 + 4 * g];
        z0 += ev.x * wr[1 + 4 * g][0]; z1 += ev.x * wr[1 + 4 * g][1];
        z0 += ev.y * wr[2 + 4 * g][0]; z1 += ev.y * wr[2 + 4 * g][1];
        z0 += ev.z * wr[3 + 4 * g][0]; z1 += ev.z * wr[3 + 4 * g][1];
        z0 += ev.w * wr[4 + 4 * g][0]; z1 += ev.w * wr[4 + 4 * g][1];
      }
      unsigned pk = ((unsigned)bf16rne(silu_f(z1)) << 16) | bf16rne(silu_f(z0));
      int byte = (e * 256 + c0 * 2) ^ ((e & 7) << 4);
      *(unsigned*)((char*)o1 + byte) = pk;
    }

    // --- issue next tile's metadata loads (hidden under GEMM1) ---
    if (nxt < NT) load_meta(nxt, nb);

    // --- GEMM1: msg_pre = o1 @ We2 + be2 ---
    bf16x8 af[4];
#pragma unroll
    for (int kk = 0; kk < 4; ++kk) {
      int byte = (cl * 256 + kk * 64 + kg * 16) ^ ((cl & 7) << 4);
      af[kk] = *(bf16x8*)((char*)o1 + byte);
    }
    f32x4 acc[8];
#pragma unroll
    for (int b = 0; b < 8; ++b) {
      acc[b] = (f32x4){be2v[b], be2v[b], be2v[b], be2v[b]};
#pragma unroll
      for (int kk = 0; kk < 4; ++kk) {
        int byte = ((b * 16 + cl) * 256 + kk * 64 + kg * 16) ^ ((cl & 7) << 4);
        bf16x8 bfr = *(bf16x8*)((char*)We2T + byte);
        acc[b] = __builtin_amdgcn_mfma_f32_16x16x32_bf16(af[kk], bfr, acc[b], 0, 0, 0);
      }
    }

    // --- issue next tile's u/w gathers into registers (hidden below) ---
    float2 uu2[16], ww2[16];
    if (nxt < NT) {
#pragma unroll
      for (int e = 0; e < 16; ++e) {
        int s = mis[wv][nb][e];
        int d = mis[wv][nb][16 + e];
        uu2[e] = *(const float2*)&u[(long)s * DM + c0];
        ww2[e] = *(const float2*)&w[(long)d * DM + c0];
      }
    }

    // --- msg = silu -> agg atomics (fp32) + restore to o1 (A-layout bf16) ---
    const int rbase = kg * 4;
#pragma unroll
    for (int b = 0; b < 8; ++b) {
      int col = b * 16 + cl;
#pragma unroll
      for (int r = 0; r < 4; ++r) {
        int row = rbase + r;
        float m = silu_f(acc[b][r]);
        atomicAdd(&agg[(long)miw[16 + row] * DM + col], m);
        int byte = (row * 256 + col * 2) ^ ((row & 7) << 4);
        *(unsigned short*)((char*)o1 + byte) = bf16rne(m);
      }
    }

    // --- GEMM2: xh = msg @ Wx1 + bx1 ---
    bf16x8 af2[4];
#pragma unroll
    for (int kk = 0; kk < 4; ++kk) {
      int byte = (cl * 256 + kk * 64 + kg * 16) ^ ((cl & 7) << 4);
      af2[kk] = *(bf16x8*)((char*)o1 + byte);
    }
    f32x4 accx[8];
#pragma unroll
    for (int b = 0; b < 8; ++b) {
      accx[b] = (f32x4){bx1v[b], bx1v[b], bx1v[b], bx1v[b]};
#pragma unroll
      for (int kk = 0; kk < 4; ++kk) {
        int byte = ((b * 16 + cl) * 256 + kk * 64 + kg * 16) ^ ((cl & 7) << 4);
        bf16x8 bfr = *(bf16x8*)((char*)Wx1T + byte);
        accx[b] = __builtin_amdgcn_mfma_f32_16x16x32_bf16(af2[kk], bfr, accx[b], 0, 0, 0);
      }
    }

    // --- weight = silu(xh) @ Wx2 + bx2, reduce over cols ---
    float s0 = 0.f, s1 = 0.f, s2 = 0.f, s3 = 0.f;
#pragma unroll
    for (int b = 0; b < 8; ++b) {
      s0 += silu_f(accx[b][0]) * wxr[b];
      s1 += silu_f(accx[b][1]) * wxr[b];
      s2 += silu_f(accx[b][2]) * wxr[b];
      s3 += silu_f(accx[b][3]) * wxr[b];
    }
#pragma unroll
    for (int off = 1; off < 16; off <<= 1) {
      s0 += __shfl_xor(s0, off, 64);
      s1 += __shfl_xor(s1, off, 64);
      s2 += __shfl_xor(s2, off, 64);
      s3 += __shfl_xor(s3, off, 64);
    }

    // --- coord atomics: 12 lanes/group -> (r,c) for rows kg*4+r ---
    if (cl < 12) {
      int r = cl / 3;
      int c = cl - 3 * r;
      float sv = (r == 0) ? s0 : ((r == 1) ? s1 : ((r == 2) ? s2 : s3));
      int row = rbase + r;
      float wgt = sv + bx2s;
      int s = miw[row];
      float dcomp = mfw[16 + c * 16 + row];
      atomicAdd(&crd[(long)s * 3 + c], dcomp * wgt);
    }

    // --- rotate pipeline ---
    if (nxt < NT) {
#pragma unroll
      for (int e = 0; e < 16; ++e) { uu[e] = uu2[e]; ww[e] = ww2[e]; }
    }
    cur = nb;
  }
}

// --- node update layer 1: t = silu([h, agg/cnt] @ Wh1 + bh1) ---
__global__ __launch_bounds__(256)
void node_upd1_kernel(const float* __restrict__ h, const float* __restrict__ agg,
                      const float* __restrict__ cnt, const float* __restrict__ Wh1,
                      const float* __restrict__ bh1, float* __restrict__ t)
{
  __shared__ float hs[4][8 * DH];
  __shared__ float as_[4][8 * DM];
  const int tid = threadIdx.x;
  const int lane = tid & 63;
  const int wv = tid >> 6;
  const int c0 = lane * 2;
  const float b0 = bh1[c0], b1 = bh1[c0 + 1];
  const int waveId = blockIdx.x * 4 + wv;
  const int nW = gridDim.x * 4;
  for (int tile = waveId; tile < NN / 8; tile += nW) {
    const long rbase = (long)tile * 8;
#pragma unroll
    for (int i = 0; i < 4; ++i) {
      int f = lane + 64 * i;
      ((float4*)&hs[wv][0])[f] = ((const float4*)(h + rbase * DH))[f];
      float cv = cnt[rbase + (f >> 5)];
      float inv = __fdividef(1.0f, fmaxf(cv, 1.0f));
      float4 av = ((const float4*)(agg + rbase * DM))[f];
      av.x *= inv; av.y *= inv; av.z *= inv; av.w *= inv;
      ((float4*)&as_[wv][0])[f] = av;
    }
    float acc[8][2];
#pragma unroll
    for (int r = 0; r < 8; ++r) { acc[r][0] = b0; acc[r][1] = b1; }
    for (int k = 0; k < DH; k += 4) {
      float2 w0 = *(const float2*)&Wh1[(k + 0) * DM + c0];
      float2 w1 = *(const float2*)&Wh1[(k + 1) * DM + c0];
      float2 w2 = *(const float2*)&Wh1[(k + 2) * DM + c0];
      float2 w3 = *(const float2*)&Wh1[(k + 3) * DM + c0];
#pragma unroll
      for (int r = 0; r < 8; ++r) {
        float4 hv = *(const float4*)&hs[wv][r * DH + k];
        acc[r][0] += hv.x * w0.x; acc[r][1] += hv.x * w0.y;
        acc[r][0] += hv.y * w1.x; acc[r][1] += hv.y * w1.y;
        acc[r][0] += hv.z * w2.x; acc[r][1] += hv.z * w2.y;
        acc[r][0] += hv.w * w3.x; acc[r][1] += hv.w * w3.y;
      }
    }
    for (int k = 0; k < DM; k += 4) {
      float2 w0 = *(const float2*)&Wh1[(DH + k + 0) * DM + c0];
      float2 w1 = *(const float2*)&Wh1[(DH + k + 1) * DM + c0];
      float2 w2 = *(const float2*)&Wh1[(DH + k + 2) * DM + c0];
      float2 w3 = *(const float2*)&Wh1[(DH + k + 3) * DM + c0];
#pragma unroll
      for (int r = 0; r < 8; ++r) {
        float4 av = *(const float4*)&as_[wv][r * DM + k];
        acc[r][0] += av.x * w0.x; acc[r][1] += av.x * w0.y;
        acc[r][0] += av.y * w1.x; acc[r][1] += av.y * w1.y;
        acc[r][0] += av.z * w2.x; acc[r][1] += av.z * w2.y;
        acc[r][0] += av.w * w3.x; acc[r][1] += av.w * w3.y;
      }
    }
#pragma unroll
    for (int r = 0; r < 8; ++r)
      *(float2*)&t[(rbase + r) * DM + c0] =
          make_float2(silu_f(acc[r][0]), silu_f(acc[r][1]));
  }
}

// --- node update layer 2 + residual + layernorm ---
__global__ __launch_bounds__(256)
void node_upd2_kernel(const float* __restrict__ t, const float* __restrict__ h,
                      const float* __restrict__ Wh2, const float* __restrict__ bh2,
                      const float* __restrict__ lng, const float* __restrict__ lnb,
                      float* __restrict__ out)
{
  __shared__ float ts[4][8 * DM];
  const int tid = threadIdx.x;
  const int lane = tid & 63;
  const int wv = tid >> 6;
  const int c0 = lane * 2;
  const float b0 = bh2[c0], b1 = bh2[c0 + 1];
  const float g0 = lng[c0], g1 = lng[c0 + 1];
  const float q0 = lnb[c0], q1 = lnb[c0 + 1];
  const int waveId = blockIdx.x * 4 + wv;
  const int nW = gridDim.x * 4;
  for (int tile = waveId; tile < NN / 8; tile += nW) {
    const long rbase = (long)tile * 8;
#pragma unroll
    for (int i = 0; i < 4; ++i) {
      int f = lane + 64 * i;
      ((float4*)&ts[wv][0])[f] = ((const float4*)(t + rbase * DM))[f];
    }
    float acc[8][2];
#pragma unroll
    for (int r = 0; r < 8; ++r) { acc[r][0] = b0; acc[r][1] = b1; }
    for (int k = 0; k < DM; k += 4) {
      float2 w0 = *(const float2*)&Wh2[(k + 0) * DM + c0];
      float2 w1 = *(const float2*)&Wh2[(k + 1) * DM + c0];
      float2 w2 = *(const float2*)&Wh2[(k + 2) * DM + c0];
      float2 w3 = *(const float2*)&Wh2[(k + 3) * DM + c0];
#pragma unroll
      for (int r = 0; r < 8; ++r) {
        float4 tv = *(const float4*)&ts[wv][r * DM + k];
        acc[r][0] += tv.x * w0.x; acc[r][1] += tv.x * w0.y;
        acc[r][0] += tv.y * w1.x; acc[r][1] += tv.y * w1.y;
        acc[r][0] += tv.z * w2.x; acc[r][1] += tv.z * w2.y;
        acc[r][0] += tv.w * w3.x; acc[r][1] += tv.w * w3.y;
      }
    }
#pragma unroll
    for (int r = 0; r < 8; ++r) {
      float2 hv = *(const float2*)&h[(rbase + r) * DH + c0];
      float p0 = acc[r][0] + hv.x;
      float p1 = acc[r][1] + hv.y;
      float s = p0 + p1;
      float q = p0 * p0 + p1 * p1;
#pragma unroll
      for (int off = 32; off > 0; off >>= 1) {
        s += __shfl_xor(s, off, 64);
        q += __shfl_xor(q, off, 64);
      }
      float mean = s * (1.0f / 128.0f);
      float var = q * (1.0f / 128.0f) - mean * mean;
      float rs = rsqrtf(var + 1e-5f);
      float y0 = (p0 - mean) * rs * g0 + q0;
      float y1 = (p1 - mean) * rs * g1 + q1;
      *(float2*)&out[(rbase + r) * DM + c0] = make_float2(y0, y1);
    }
  }
}

// --- x output ---
__global__ __launch_bounds__(256)
void xout_kernel(const float* __restrict__ x, const float* __restrict__ crd,
                 const float* __restrict__ cnt, float* __restrict__ out)
{
  int i = blockIdx.x * 256 + threadIdx.x;
  if (i < NN * 3) {
    int n = i / 3;
    float cv = fmaxf(cnt[n], 1.0f);
    out[i] = x[i] + crd[i] * __fdividef(1.0f, cv);
  }
}

extern "C" void kernel_launch(void* const* d_in, const int* in_sizes, int n_in,
                              void* d_out, int out_size, void* d_ws, size_t ws_size,
                              hipStream_t stream)
{
  (void)in_sizes; (void)n_in; (void)out_size; (void)ws_size;
  const float* h   = (const float*)d_in[0];
  const float* x   = (const float*)d_in[1];
  const float* ea  = (const float*)d_in[2];
  const float* We1 = (const float*)d_in[3];
  const float* be1 = (const float*)d_in[4];
  const float* We2 = (const float*)d_in[5];
  const float* be2 = (const float*)d_in[6];
  const float* Wh1 = (const float*)d_in[7];
  const float* bh1 = (const float*)d_in[8];
  const float* Wh2 = (const float*)d_in[9];
  const float* bh2 = (const float*)d_in[10];
  const float* Wx1 = (const float*)d_in[11];
  const float* bx1 = (const float*)d_in[12];
  const float* Wx2 = (const float*)d_in[13];
  const float* bx2 = (const float*)d_in[14];
  const float* lng = (const float*)d_in[15];
  const float* lnb = (const float*)d_in[16];
  const int*   ei  = (const int*)d_in[17];
  float* out = (float*)d_out;
  float* ws  = (float*)d_ws;

  float* u   = ws;                 // N*128
  float* w   = ws + 6400000;       // N*128
  float* agg = ws + 12800000;      // N*128
  float* cnt = ws + 19200000;      // N
  float* crd = ws + 19250000;      // N*3
  float* t   = u;                  // reuse u after edge kernel

  hipMemsetAsync(agg, 0, (6400000 + 50000 + 150000) * sizeof(float), stream);

  node_pre_kernel<<<1563, 256, 0, stream>>>(h, We1, u, w);
  count_kernel<<<(EE + 255) / 256, 256, 0, stream>>>(ei, cnt);
  edge_kernel<<<256, 512, 0, stream>>>(u, w, x, ea, We1, be1, We2, be2,
                                       Wx1, bx1, Wx2, bx2, ei, agg, crd);
  node_upd1_kernel<<<1563, 256, 0, stream>>>(h, agg, cnt, Wh1, bh1, t);
  node_upd2_kernel<<<1563, 256, 0, stream>>>(t, h, Wh2, bh2, lng, lnb, out);
  xout_kernel<<<(NN * 3 + 255) / 256, 256, 0, stream>>>(x, crd, cnt, out + 6400000);
}

// Round 9
// 661.726 us; speedup vs baseline: 2.0983x; 1.3574x over previous
//
#include <hip/hip_runtime.h>

constexpr int NN = 50000;
constexpr int EE = 800000;
constexpr int DH = 128;
constexpr int DE = 16;
constexpr int DM = 128;

typedef short bf16x8 __attribute__((ext_vector_type(8)));
typedef float f32x4 __attribute__((ext_vector_type(4)));

__device__ __forceinline__ float silu_f(float z) {
  return __fdividef(z, 1.0f + __expf(-z));
}
__device__ __forceinline__ unsigned short bf16rne(float f) {
  unsigned u = __float_as_uint(f);
  return (unsigned short)((u + 0x7FFFu + ((u >> 16) & 1u)) >> 16);
}

// --- prep: transpose weights to bf16 [n][k] row-major in global ---
__global__ __launch_bounds__(256)
void prep_wt_kernel(const float* __restrict__ We1, const float* __restrict__ Wh1,
                    const float* __restrict__ Wh2,
                    unsigned short* __restrict__ WeaT, unsigned short* __restrict__ WebT,
                    unsigned short* __restrict__ Wh1T, unsigned short* __restrict__ Wh2T)
{
  int i = blockIdx.x * 256 + threadIdx.x;
  if (i < 16384) {
    int n = i >> 7, k = i & 127;
    WeaT[n * 128 + k] = bf16rne(We1[k * DM + n]);
    WebT[n * 128 + k] = bf16rne(We1[(DH + k) * DM + n]);
    Wh2T[n * 128 + k] = bf16rne(Wh2[k * DM + n]);
  }
  if (i < 32768) {
    int n = i >> 8, k = i & 255;
    Wh1T[n * 256 + k] = bf16rne(Wh1[k * DM + n]);
  }
}

// --- node precompute via MFMA: u = h @ We1[0:128], w = h @ We1[128:256] ---
__global__ __launch_bounds__(256, 2)
void node_pre_mfma(const float* __restrict__ h,
                   const unsigned short* __restrict__ WeaT,
                   const unsigned short* __restrict__ WebT,
                   float* __restrict__ u, float* __restrict__ w)
{
  __shared__ unsigned short Ba[DM * DM];  // swizzled: byte ^= (n&7)<<4
  __shared__ unsigned short Bb[DM * DM];
  const int tid = threadIdx.x;
  for (int c = tid; c < 2048; c += 256) {
    int n = c >> 4, ck = c & 15;   // 16 chunks of 8 per 128-elem row
    int sb = (n * 256 + ck * 16) ^ ((n & 7) << 4);
    *(bf16x8*)((char*)Ba + sb) = ((const bf16x8*)WeaT)[c];
    *(bf16x8*)((char*)Bb + sb) = ((const bf16x8*)WebT)[c];
  }
  __syncthreads();
  const int lane = tid & 63, wv = tid >> 6;
  const int cl = lane & 15, kg = lane >> 4;
  const int waveId = blockIdx.x * 4 + wv, nW = gridDim.x * 4;
  for (int tile = waveId; tile < NN / 16; tile += nW) {
    const long rbase = (long)tile * 16;
    bf16x8 af[4];
#pragma unroll
    for (int kk = 0; kk < 4; ++kk) {
      const float* hp = &h[(rbase + cl) * DH + kk * 32 + kg * 8];
      float4 a0 = *(const float4*)hp;
      float4 a1 = *(const float4*)(hp + 4);
      bf16x8 v;
      v[0] = (short)bf16rne(a0.x); v[1] = (short)bf16rne(a0.y);
      v[2] = (short)bf16rne(a0.z); v[3] = (short)bf16rne(a0.w);
      v[4] = (short)bf16rne(a1.x); v[5] = (short)bf16rne(a1.y);
      v[6] = (short)bf16rne(a1.z); v[7] = (short)bf16rne(a1.w);
      af[kk] = v;
    }
#pragma unroll
    for (int b = 0; b < 8; ++b) {
      f32x4 acc = (f32x4){0.f, 0.f, 0.f, 0.f};
      f32x4 acw = (f32x4){0.f, 0.f, 0.f, 0.f};
#pragma unroll
      for (int kk = 0; kk < 4; ++kk) {
        int byte = ((b * 16 + cl) * 256 + kk * 64 + kg * 16) ^ ((cl & 7) << 4);
        acc = __builtin_amdgcn_mfma_f32_16x16x32_bf16(af[kk], *(bf16x8*)((char*)Ba + byte), acc, 0, 0, 0);
        acw = __builtin_amdgcn_mfma_f32_16x16x32_bf16(af[kk], *(bf16x8*)((char*)Bb + byte), acw, 0, 0, 0);
      }
      int col = b * 16 + cl;
#pragma unroll
      for (int r = 0; r < 4; ++r) {
        long row = rbase + kg * 4 + r;
        u[row * DM + col] = acc[r];
        w[row * DM + col] = acw[r];
      }
    }
  }
}

// --- dst-degree count ---
__global__ __launch_bounds__(256)
void count_kernel(const int* __restrict__ ei, float* __restrict__ cnt)
{
  int e = blockIdx.x * 256 + threadIdx.x;
  if (e < EE) atomicAdd(&cnt[ei[EE + e]], 1.0f);
}

// --- fused edge kernel: EXACT round-2 structure (best verified: 555 us) ---
__global__ __launch_bounds__(512, 2)
void edge_kernel(const float* __restrict__ u, const float* __restrict__ w,
                 const float* __restrict__ x, const float* __restrict__ ea,
                 const float* __restrict__ We1, const float* __restrict__ be1,
                 const float* __restrict__ We2, const float* __restrict__ be2,
                 const float* __restrict__ Wx1, const float* __restrict__ bx1,
                 const float* __restrict__ Wx2, const float* __restrict__ bx2,
                 const int* __restrict__ ei,
                 float* __restrict__ agg, float* __restrict__ crd)
{
  __shared__ unsigned short We2T[DM * DM];
  __shared__ unsigned short Wx1T[DM * DM];
  __shared__ unsigned short o1s[8][16 * DM];
  __shared__ float mfs[8][64];
  __shared__ float eas[8][256];
  __shared__ int   mis[8][32];

  const int tid = threadIdx.x;
  for (int idx = tid; idx < DM * DM; idx += 512) {
    int k = idx >> 7, n = idx & 127;
    int byte = (n * 256 + k * 2) ^ ((n & 7) << 4);
    *(unsigned short*)((char*)We2T + byte) = bf16rne(We2[idx]);
    *(unsigned short*)((char*)Wx1T + byte) = bf16rne(Wx1[idx]);
  }
  __syncthreads();

  const int lane = tid & 63;
  const int wv = tid >> 6;
  const int cl = lane & 15;
  const int kg = lane >> 4;
  const int c0 = lane * 2;
  unsigned short* o1 = o1s[wv];
  float* mfw = mfs[wv];
  float* eaw = eas[wv];
  int* miw = mis[wv];

  float wr[17][2];
#pragma unroll
  for (int t = 0; t < 17; ++t) {
    wr[t][0] = We1[(2 * DH + t) * DM + c0];
    wr[t][1] = We1[(2 * DH + t) * DM + c0 + 1];
  }
  const float be1a = be1[c0], be1b = be1[c0 + 1];
  float be2v[8], bx1v[8], wxr[8];
#pragma unroll
  for (int b = 0; b < 8; ++b) {
    be2v[b] = be2[b * 16 + cl];
    bx1v[b] = bx1[b * 16 + cl];
    wxr[b] = Wx2[b * 16 + cl];
  }
  const float bx2s = bx2[0];

  const int waveId = blockIdx.x * 8 + wv;
  const int nW = gridDim.x * 8;

  for (int tile = waveId; tile < EE / 16; tile += nW) {
    const int e0 = tile * 16;
    if (lane < 16) {
      int s = ei[e0 + lane];
      int d = ei[EE + e0 + lane];
      miw[lane] = s;
      miw[16 + lane] = d;
      float dx = x[s * 3 + 0] - x[d * 3 + 0];
      float dy = x[s * 3 + 1] - x[d * 3 + 1];
      float dz = x[s * 3 + 2] - x[d * 3 + 2];
      mfw[lane] = dx * dx + dy * dy + dz * dz;
      mfw[16 + lane] = dx;
      mfw[32 + lane] = dy;
      mfw[48 + lane] = dz;
    }
    ((float4*)eaw)[lane] = ((const float4*)(ea + (long)e0 * DE))[lane];

#pragma unroll
    for (int e = 0; e < 16; ++e) {
      int s = miw[e], d = miw[16 + e];
      float2 uu = *(const float2*)&u[(long)s * DM + c0];
      float2 ww = *(const float2*)&w[(long)d * DM + c0];
      float sq = mfw[e];
      float z0 = uu.x + ww.x + be1a + sq * wr[0][0];
      float z1 = uu.y + ww.y + be1b + sq * wr[0][1];
#pragma unroll
      for (int g = 0; g < 4; ++g) {
        float4 ev = *(const float4*)&eaw[e * 16 + 4 * g];
        z0 += ev.x * wr[1 + 4 * g][0]; z1 += ev.x * wr[1 + 4 * g][1];
        z0 += ev.y * wr[2 + 4 * g][0]; z1 += ev.y * wr[2 + 4 * g][1];
        z0 += ev.z * wr[3 + 4 * g][0]; z1 += ev.z * wr[3 + 4 * g][1];
        z0 += ev.w * wr[4 + 4 * g][0]; z1 += ev.w * wr[4 + 4 * g][1];
      }
      unsigned pk = ((unsigned)bf16rne(silu_f(z1)) << 16) | bf16rne(silu_f(z0));
      int byte = (e * 256 + c0 * 2) ^ ((e & 7) << 4);
      *(unsigned*)((char*)o1 + byte) = pk;
    }

    bf16x8 af[4];
#pragma unroll
    for (int kk = 0; kk < 4; ++kk) {
      int byte = (cl * 256 + kk * 64 + kg * 16) ^ ((cl & 7) << 4);
      af[kk] = *(bf16x8*)((char*)o1 + byte);
    }
    f32x4 acc[8];
#pragma unroll
    for (int b = 0; b < 8; ++b) {
      acc[b] = (f32x4){be2v[b], be2v[b], be2v[b], be2v[b]};
#pragma unroll
      for (int kk = 0; kk < 4; ++kk) {
        int byte = ((b * 16 + cl) * 256 + kk * 64 + kg * 16) ^ ((cl & 7) << 4);
        bf16x8 bfr = *(bf16x8*)((char*)We2T + byte);
        acc[b] = __builtin_amdgcn_mfma_f32_16x16x32_bf16(af[kk], bfr, acc[b], 0, 0, 0);
      }
    }

    const int rbase = kg * 4;
#pragma unroll
    for (int b = 0; b < 8; ++b) {
      int col = b * 16 + cl;
#pragma unroll
      for (int r = 0; r < 4; ++r) {
        int row = rbase + r;
        float m = silu_f(acc[b][r]);
        atomicAdd(&agg[(long)miw[16 + row] * DM + col], m);
        int byte = (row * 256 + col * 2) ^ ((row & 7) << 4);
        *(unsigned short*)((char*)o1 + byte) = bf16rne(m);
      }
    }

    bf16x8 af2[4];
#pragma unroll
    for (int kk = 0; kk < 4; ++kk) {
      int byte = (cl * 256 + kk * 64 + kg * 16) ^ ((cl & 7) << 4);
      af2[kk] = *(bf16x8*)((char*)o1 + byte);
    }
    f32x4 accx[8];
#pragma unroll
    for (int b = 0; b < 8; ++b) {
      accx[b] = (f32x4){bx1v[b], bx1v[b], bx1v[b], bx1v[b]};
#pragma unroll
      for (int kk = 0; kk < 4; ++kk) {
        int byte = ((b * 16 + cl) * 256 + kk * 64 + kg * 16) ^ ((cl & 7) << 4);
        bf16x8 bfr = *(bf16x8*)((char*)Wx1T + byte);
        accx[b] = __builtin_amdgcn_mfma_f32_16x16x32_bf16(af2[kk], bfr, accx[b], 0, 0, 0);
      }
    }

    float s0 = 0.f, s1 = 0.f, s2 = 0.f, s3 = 0.f;
#pragma unroll
    for (int b = 0; b < 8; ++b) {
      s0 += silu_f(accx[b][0]) * wxr[b];
      s1 += silu_f(accx[b][1]) * wxr[b];
      s2 += silu_f(accx[b][2]) * wxr[b];
      s3 += silu_f(accx[b][3]) * wxr[b];
    }
#pragma unroll
    for (int off = 1; off < 16; off <<= 1) {
      s0 += __shfl_xor(s0, off, 64);
      s1 += __shfl_xor(s1, off, 64);
      s2 += __shfl_xor(s2, off, 64);
      s3 += __shfl_xor(s3, off, 64);
    }

    if (cl < 12) {
      int r = cl / 3;
      int c = cl - 3 * r;
      float sv = (r == 0) ? s0 : ((r == 1) ? s1 : ((r == 2) ? s2 : s3));
      int row = rbase + r;
      float wgt = sv + bx2s;
      int s = miw[row];
      float dcomp = mfw[16 + c * 16 + row];
      atomicAdd(&crd[(long)s * 3 + c], dcomp * wgt);
    }
  }
}

// --- node update layer 1 via MFMA: t = silu([h, agg/cnt] @ Wh1 + bh1), bf16 out ---
__global__ __launch_bounds__(256, 2)
void upd1_mfma(const float* __restrict__ h, const float* __restrict__ agg,
               const float* __restrict__ cnt, const unsigned short* __restrict__ Wh1T,
               const float* __restrict__ bh1, unsigned short* __restrict__ t)
{
  __shared__ unsigned short B1[DM * 256];  // [n][k=256], swizzled byte ^= (n&7)<<4
  const int tid = threadIdx.x;
  for (int c = tid; c < 4096; c += 256) {
    int n = c >> 5, ck = c & 31;   // 32 chunks of 8 per 256-elem row
    int sb = (n * 512 + ck * 16) ^ ((n & 7) << 4);
    *(bf16x8*)((char*)B1 + sb) = ((const bf16x8*)Wh1T)[c];
  }
  __syncthreads();
  const int lane = tid & 63, wv = tid >> 6;
  const int cl = lane & 15, kg = lane >> 4;
  float bh1v[8];
#pragma unroll
  for (int b = 0; b < 8; ++b) bh1v[b] = bh1[b * 16 + cl];
  const int waveId = blockIdx.x * 4 + wv, nW = gridDim.x * 4;
  for (int tile = waveId; tile < NN / 16; tile += nW) {
    const long rbase = (long)tile * 16;
    const float inv = __fdividef(1.0f, fmaxf(cnt[rbase + cl], 1.0f));
    bf16x8 af[8];
#pragma unroll
    for (int kk = 0; kk < 4; ++kk) {
      const float* hp = &h[(rbase + cl) * DH + kk * 32 + kg * 8];
      float4 a0 = *(const float4*)hp;
      float4 a1 = *(const float4*)(hp + 4);
      bf16x8 v;
      v[0] = (short)bf16rne(a0.x); v[1] = (short)bf16rne(a0.y);
      v[2] = (short)bf16rne(a0.z); v[3] = (short)bf16rne(a0.w);
      v[4] = (short)bf16rne(a1.x); v[5] = (short)bf16rne(a1.y);
      v[6] = (short)bf16rne(a1.z); v[7] = (short)bf16rne(a1.w);
      af[kk] = v;
    }
#pragma unroll
    for (int kk = 0; kk < 4; ++kk) {
      const float* ap = &agg[(rbase + cl) * DM + kk * 32 + kg * 8];
      float4 a0 = *(const float4*)ap;
      float4 a1 = *(const float4*)(ap + 4);
      bf16x8 v;
      v[0] = (short)bf16rne(a0.x * inv); v[1] = (short)bf16rne(a0.y * inv);
      v[2] = (short)bf16rne(a0.z * inv); v[3] = (short)bf16rne(a0.w * inv);
      v[4] = (short)bf16rne(a1.x * inv); v[5] = (short)bf16rne(a1.y * inv);
      v[6] = (short)bf16rne(a1.z * inv); v[7] = (short)bf16rne(a1.w * inv);
      af[4 + kk] = v;
    }
#pragma unroll
    for (int b = 0; b < 8; ++b) {
      f32x4 acc = (f32x4){bh1v[b], bh1v[b], bh1v[b], bh1v[b]};
#pragma unroll
      for (int kk = 0; kk < 8; ++kk) {
        int byte = ((b * 16 + cl) * 512 + kk * 64 + kg * 16) ^ ((cl & 7) << 4);
        acc = __builtin_amdgcn_mfma_f32_16x16x32_bf16(af[kk], *(bf16x8*)((char*)B1 + byte), acc, 0, 0, 0);
      }
      int col = b * 16 + cl;
#pragma unroll
      for (int r = 0; r < 4; ++r) {
        long row = rbase + kg * 4 + r;
        t[row * DM + col] = bf16rne(silu_f(acc[r]));
      }
    }
  }
}

// --- node update layer 2 via MFMA + residual + layernorm ---
__global__ __launch_bounds__(256, 2)
void upd2_mfma(const unsigned short* __restrict__ t, const float* __restrict__ h,
               const unsigned short* __restrict__ Wh2T, const float* __restrict__ bh2,
               const float* __restrict__ lng, const float* __restrict__ lnb,
               float* __restrict__ out)
{
  __shared__ unsigned short B2[DM * DM];
  const int tid = threadIdx.x;
  for (int c = tid; c < 2048; c += 256) {
    int n = c >> 4, ck = c & 15;   // 16 chunks of 8 per 128-elem row
    int sb = (n * 256 + ck * 16) ^ ((n & 7) << 4);
    *(bf16x8*)((char*)B2 + sb) = ((const bf16x8*)Wh2T)[c];
  }
  __syncthreads();
  const int lane = tid & 63, wv = tid >> 6;
  const int cl = lane & 15, kg = lane >> 4;
  float bh2v[8], gv[8], qv[8];
#pragma unroll
  for (int b = 0; b < 8; ++b) {
    bh2v[b] = bh2[b * 16 + cl];
    gv[b] = lng[b * 16 + cl];
    qv[b] = lnb[b * 16 + cl];
  }
  const int waveId = blockIdx.x * 4 + wv, nW = gridDim.x * 4;
  for (int tile = waveId; tile < NN / 16; tile += nW) {
    const long rbase = (long)tile * 16;
    bf16x8 af[4];
#pragma unroll
    for (int kk = 0; kk < 4; ++kk)
      af[kk] = *(const bf16x8*)&t[(rbase + cl) * DM + kk * 32 + kg * 8];
    float pre[8][4];
#pragma unroll
    for (int b = 0; b < 8; ++b) {
      f32x4 acc = (f32x4){bh2v[b], bh2v[b], bh2v[b], bh2v[b]};
#pragma unroll
      for (int kk = 0; kk < 4; ++kk) {
        int byte = ((b * 16 + cl) * 256 + kk * 64 + kg * 16) ^ ((cl & 7) << 4);
        acc = __builtin_amdgcn_mfma_f32_16x16x32_bf16(af[kk], *(bf16x8*)((char*)B2 + byte), acc, 0, 0, 0);
      }
      int col = b * 16 + cl;
#pragma unroll
      for (int r = 0; r < 4; ++r)
        pre[b][r] = acc[r] + h[(rbase + kg * 4 + r) * DH + col];
    }
#pragma unroll
    for (int r = 0; r < 4; ++r) {
      float s = 0.f, q = 0.f;
#pragma unroll
      for (int b = 0; b < 8; ++b) { s += pre[b][r]; q += pre[b][r] * pre[b][r]; }
#pragma unroll
      for (int off = 1; off < 16; off <<= 1) {
        s += __shfl_xor(s, off, 64);
        q += __shfl_xor(q, off, 64);
      }
      float mean = s * (1.0f / 128.0f);
      float var = q * (1.0f / 128.0f) - mean * mean;
      float rs = rsqrtf(var + 1e-5f);
      long row = rbase + kg * 4 + r;
#pragma unroll
      for (int b = 0; b < 8; ++b) {
        out[row * DM + b * 16 + cl] = (pre[b][r] - mean) * rs * gv[b] + qv[b];
      }
    }
  }
}

// --- x output ---
__global__ __launch_bounds__(256)
void xout_kernel(const float* __restrict__ x, const float* __restrict__ crd,
                 const float* __restrict__ cnt, float* __restrict__ out)
{
  int i = blockIdx.x * 256 + threadIdx.x;
  if (i < NN * 3) {
    int n = i / 3;
    float cv = fmaxf(cnt[n], 1.0f);
    out[i] = x[i] + crd[i] * __fdividef(1.0f, cv);
  }
}

extern "C" void kernel_launch(void* const* d_in, const int* in_sizes, int n_in,
                              void* d_out, int out_size, void* d_ws, size_t ws_size,
                              hipStream_t stream)
{
  (void)in_sizes; (void)n_in; (void)out_size; (void)ws_size;
  const float* h   = (const float*)d_in[0];
  const float* x   = (const float*)d_in[1];
  const float* ea  = (const float*)d_in[2];
  const float* We1 = (const float*)d_in[3];
  const float* be1 = (const float*)d_in[4];
  const float* We2 = (const float*)d_in[5];
  const float* be2 = (const float*)d_in[6];
  const float* Wh1 = (const float*)d_in[7];
  const float* bh1 = (const float*)d_in[8];
  const float* Wh2 = (const float*)d_in[9];
  const float* bh2 = (const float*)d_in[10];
  const float* Wx1 = (const float*)d_in[11];
  const float* bx1 = (const float*)d_in[12];
  const float* Wx2 = (const float*)d_in[13];
  const float* bx2 = (const float*)d_in[14];
  const float* lng = (const float*)d_in[15];
  const float* lnb = (const float*)d_in[16];
  const int*   ei  = (const int*)d_in[17];
  float* out = (float*)d_out;
  float* ws  = (float*)d_ws;

  float* u   = ws;                 // N*128 fp32
  float* w   = ws + 6400000;       // N*128 fp32
  float* agg = ws + 12800000;      // N*128 fp32
  float* cnt = ws + 19200000;      // N
  float* crd = ws + 19250000;      // N*3
  unsigned short* WeaT = (unsigned short*)(ws + 19400000);  // 128*128
  unsigned short* WebT = WeaT + 16384;                      // 128*128
  unsigned short* Wh1T = WebT + 16384;                      // 128*256
  unsigned short* Wh2T = Wh1T + 32768;                      // 128*128
  unsigned short* tbf  = (unsigned short*)w;                // reuse w after edge

  hipMemsetAsync(agg, 0, (6400000 + 50000 + 150000) * sizeof(float), stream);

  prep_wt_kernel<<<128, 256, 0, stream>>>(We1, Wh1, Wh2, WeaT, WebT, Wh1T, Wh2T);
  node_pre_mfma<<<782, 256, 0, stream>>>(h, WeaT, WebT, u, w);
  count_kernel<<<(EE + 255) / 256, 256, 0, stream>>>(ei, cnt);
  edge_kernel<<<256, 512, 0, stream>>>(u, w, x, ea, We1, be1, We2, be2,
                                       Wx1, bx1, Wx2, bx2, ei, agg, crd);
  upd1_mfma<<<782, 256, 0, stream>>>(h, agg, cnt, Wh1T, bh1, tbf);
  upd2_mfma<<<782, 256, 0, stream>>>(tbf, h, Wh2T, bh2, lng, lnb, out);
  xout_kernel<<<(NN * 3 + 255) / 256, 256, 0, stream>>>(x, crd, cnt, out + 6400000);
}

// Round 10
// 661.714 us; speedup vs baseline: 2.0983x; 1.0000x over previous
//
#include <hip/hip_runtime.h>

constexpr int NN = 50000;
constexpr int EE = 800000;
constexpr int DH = 128;
constexpr int DE = 16;
constexpr int DM = 128;

typedef short bf16x8 __attribute__((ext_vector_type(8)));
typedef float f32x4 __attribute__((ext_vector_type(4)));

__device__ __forceinline__ float silu_f(float z) {
  return __fdividef(z, 1.0f + __expf(-z));
}
__device__ __forceinline__ unsigned short bf16rne(float f) {
  unsigned u = __float_as_uint(f);
  return (unsigned short)((u + 0x7FFFu + ((u >> 16) & 1u)) >> 16);
}

// --- prep: transpose weights to bf16 [n][k] row-major in global ---
__global__ __launch_bounds__(256)
void prep_wt_kernel(const float* __restrict__ We1, const float* __restrict__ Wh1,
                    const float* __restrict__ Wh2,
                    unsigned short* __restrict__ WeaT, unsigned short* __restrict__ WebT,
                    unsigned short* __restrict__ Wh1T, unsigned short* __restrict__ Wh2T)
{
  int i = blockIdx.x * 256 + threadIdx.x;
  if (i < 16384) {
    int n = i >> 7, k = i & 127;
    WeaT[n * 128 + k] = bf16rne(We1[k * DM + n]);
    WebT[n * 128 + k] = bf16rne(We1[(DH + k) * DM + n]);
    Wh2T[n * 128 + k] = bf16rne(Wh2[k * DM + n]);
  }
  if (i < 32768) {
    int n = i >> 8, k = i & 255;
    Wh1T[n * 256 + k] = bf16rne(Wh1[k * DM + n]);
  }
}

// --- node precompute via MFMA ---
__global__ __launch_bounds__(256, 2)
void node_pre_mfma(const float* __restrict__ h,
                   const unsigned short* __restrict__ WeaT,
                   const unsigned short* __restrict__ WebT,
                   float* __restrict__ u, float* __restrict__ w)
{
  __shared__ unsigned short Ba[DM * DM];
  __shared__ unsigned short Bb[DM * DM];
  const int tid = threadIdx.x;
  for (int c = tid; c < 2048; c += 256) {
    int n = c >> 4, ck = c & 15;
    int sb = (n * 256 + ck * 16) ^ ((n & 7) << 4);
    *(bf16x8*)((char*)Ba + sb) = ((const bf16x8*)WeaT)[c];
    *(bf16x8*)((char*)Bb + sb) = ((const bf16x8*)WebT)[c];
  }
  __syncthreads();
  const int lane = tid & 63, wv = tid >> 6;
  const int cl = lane & 15, kg = lane >> 4;
  const int waveId = blockIdx.x * 4 + wv, nW = gridDim.x * 4;
  for (int tile = waveId; tile < NN / 16; tile += nW) {
    const long rbase = (long)tile * 16;
    bf16x8 af[4];
#pragma unroll
    for (int kk = 0; kk < 4; ++kk) {
      const float* hp = &h[(rbase + cl) * DH + kk * 32 + kg * 8];
      float4 a0 = *(const float4*)hp;
      float4 a1 = *(const float4*)(hp + 4);
      bf16x8 v;
      v[0] = (short)bf16rne(a0.x); v[1] = (short)bf16rne(a0.y);
      v[2] = (short)bf16rne(a0.z); v[3] = (short)bf16rne(a0.w);
      v[4] = (short)bf16rne(a1.x); v[5] = (short)bf16rne(a1.y);
      v[6] = (short)bf16rne(a1.z); v[7] = (short)bf16rne(a1.w);
      af[kk] = v;
    }
#pragma unroll
    for (int b = 0; b < 8; ++b) {
      f32x4 acc = (f32x4){0.f, 0.f, 0.f, 0.f};
      f32x4 acw = (f32x4){0.f, 0.f, 0.f, 0.f};
#pragma unroll
      for (int kk = 0; kk < 4; ++kk) {
        int byte = ((b * 16 + cl) * 256 + kk * 64 + kg * 16) ^ ((cl & 7) << 4);
        acc = __builtin_amdgcn_mfma_f32_16x16x32_bf16(af[kk], *(bf16x8*)((char*)Ba + byte), acc, 0, 0, 0);
        acw = __builtin_amdgcn_mfma_f32_16x16x32_bf16(af[kk], *(bf16x8*)((char*)Bb + byte), acw, 0, 0, 0);
      }
      int col = b * 16 + cl;
#pragma unroll
      for (int r = 0; r < 4; ++r) {
        long row = rbase + kg * 4 + r;
        u[row * DM + col] = acc[r];
        w[row * DM + col] = acw[r];
      }
    }
  }
}

// --- dst-degree count ---
__global__ __launch_bounds__(256)
void count_kernel(const int* __restrict__ ei, float* __restrict__ cnt)
{
  int e = blockIdx.x * 256 + threadIdx.x;
  if (e < EE) atomicAdd(&cnt[ei[EE + e]], 1.0f);
}

// --- SPLIT kernel A: L1 + GEMM1 + silu -> agg atomics + msg store ---
__global__ __launch_bounds__(512, 4)
void edge_msg_kernel(const float* __restrict__ u, const float* __restrict__ w,
                     const float* __restrict__ x, const float* __restrict__ ea,
                     const float* __restrict__ We1, const float* __restrict__ be1,
                     const float* __restrict__ We2, const float* __restrict__ be2,
                     const int* __restrict__ ei,
                     float* __restrict__ agg, unsigned short* __restrict__ msg)
{
  __shared__ unsigned short We2T[DM * DM];
  __shared__ unsigned short o1s[8][16 * DM];
  __shared__ float sqs[8][16];
  __shared__ float eas[8][256];
  __shared__ int   mis[8][32];

  const int tid = threadIdx.x;
  for (int idx = tid; idx < DM * DM; idx += 512) {
    int k = idx >> 7, n = idx & 127;
    int byte = (n * 256 + k * 2) ^ ((n & 7) << 4);
    *(unsigned short*)((char*)We2T + byte) = bf16rne(We2[idx]);
  }
  __syncthreads();

  const int lane = tid & 63;
  const int wv = tid >> 6;
  const int cl = lane & 15;
  const int kg = lane >> 4;
  const int c0 = lane * 2;
  unsigned short* o1 = o1s[wv];
  float* sqw = sqs[wv];
  float* eaw = eas[wv];
  int* miw = mis[wv];

  float wr[17][2];
#pragma unroll
  for (int t = 0; t < 17; ++t) {
    wr[t][0] = We1[(2 * DH + t) * DM + c0];
    wr[t][1] = We1[(2 * DH + t) * DM + c0 + 1];
  }
  const float be1a = be1[c0], be1b = be1[c0 + 1];
  float be2v[8];
#pragma unroll
  for (int b = 0; b < 8; ++b) be2v[b] = be2[b * 16 + cl];

  const int waveId = blockIdx.x * 8 + wv;
  const int nW = gridDim.x * 8;

  for (int tile = waveId; tile < EE / 16; tile += nW) {
    const int e0 = tile * 16;
    if (lane < 16) {
      int s = ei[e0 + lane];
      int d = ei[EE + e0 + lane];
      miw[lane] = s;
      miw[16 + lane] = d;
      float dx = x[s * 3 + 0] - x[d * 3 + 0];
      float dy = x[s * 3 + 1] - x[d * 3 + 1];
      float dz = x[s * 3 + 2] - x[d * 3 + 2];
      sqw[lane] = dx * dx + dy * dy + dz * dz;
    }
    ((float4*)eaw)[lane] = ((const float4*)(ea + (long)e0 * DE))[lane];

#pragma unroll
    for (int e = 0; e < 16; ++e) {
      int s = miw[e], d = miw[16 + e];
      float2 uu = *(const float2*)&u[(long)s * DM + c0];
      float2 ww = *(const float2*)&w[(long)d * DM + c0];
      float sq = sqw[e];
      float z0 = uu.x + ww.x + be1a + sq * wr[0][0];
      float z1 = uu.y + ww.y + be1b + sq * wr[0][1];
#pragma unroll
      for (int g = 0; g < 4; ++g) {
        float4 ev = *(const float4*)&eaw[e * 16 + 4 * g];
        z0 += ev.x * wr[1 + 4 * g][0]; z1 += ev.x * wr[1 + 4 * g][1];
        z0 += ev.y * wr[2 + 4 * g][0]; z1 += ev.y * wr[2 + 4 * g][1];
        z0 += ev.z * wr[3 + 4 * g][0]; z1 += ev.z * wr[3 + 4 * g][1];
        z0 += ev.w * wr[4 + 4 * g][0]; z1 += ev.w * wr[4 + 4 * g][1];
      }
      unsigned pk = ((unsigned)bf16rne(silu_f(z1)) << 16) | bf16rne(silu_f(z0));
      int byte = (e * 256 + c0 * 2) ^ ((e & 7) << 4);
      *(unsigned*)((char*)o1 + byte) = pk;
    }

    bf16x8 af[4];
#pragma unroll
    for (int kk = 0; kk < 4; ++kk) {
      int byte = (cl * 256 + kk * 64 + kg * 16) ^ ((cl & 7) << 4);
      af[kk] = *(bf16x8*)((char*)o1 + byte);
    }
    f32x4 acc[8];
#pragma unroll
    for (int b = 0; b < 8; ++b) {
      acc[b] = (f32x4){be2v[b], be2v[b], be2v[b], be2v[b]};
#pragma unroll
      for (int kk = 0; kk < 4; ++kk) {
        int byte = ((b * 16 + cl) * 256 + kk * 64 + kg * 16) ^ ((cl & 7) << 4);
        bf16x8 bfr = *(bf16x8*)((char*)We2T + byte);
        acc[b] = __builtin_amdgcn_mfma_f32_16x16x32_bf16(af[kk], bfr, acc[b], 0, 0, 0);
      }
    }

    const int rbase = kg * 4;
#pragma unroll
    for (int b = 0; b < 8; ++b) {
      int col = b * 16 + cl;
#pragma unroll
      for (int r = 0; r < 4; ++r) {
        int row = rbase + r;
        float m = silu_f(acc[b][r]);
        atomicAdd(&agg[(long)miw[16 + row] * DM + col], m);
        msg[(long)(e0 + row) * DM + col] = bf16rne(m);
      }
    }
  }
}

// --- SPLIT kernel B: GEMM2 + Wx2 dot + coord atomics (msg streamed) ---
__global__ __launch_bounds__(512, 4)
void edge_coord_kernel(const unsigned short* __restrict__ msg,
                       const float* __restrict__ x,
                       const float* __restrict__ Wx1, const float* __restrict__ bx1,
                       const float* __restrict__ Wx2, const float* __restrict__ bx2,
                       const int* __restrict__ ei, float* __restrict__ crd)
{
  __shared__ unsigned short Wx1T[DM * DM];
  __shared__ float mfs[8][48];   // dx,dy,dz
  __shared__ int   mis[8][16];   // src

  const int tid = threadIdx.x;
  for (int idx = tid; idx < DM * DM; idx += 512) {
    int k = idx >> 7, n = idx & 127;
    int byte = (n * 256 + k * 2) ^ ((n & 7) << 4);
    *(unsigned short*)((char*)Wx1T + byte) = bf16rne(Wx1[idx]);
  }
  __syncthreads();

  const int lane = tid & 63;
  const int wv = tid >> 6;
  const int cl = lane & 15;
  const int kg = lane >> 4;
  float* mfw = mfs[wv];
  int* miw = mis[wv];

  float bx1v[8], wxr[8];
#pragma unroll
  for (int b = 0; b < 8; ++b) {
    bx1v[b] = bx1[b * 16 + cl];
    wxr[b] = Wx2[b * 16 + cl];
  }
  const float bx2s = bx2[0];

  const int waveId = blockIdx.x * 8 + wv;
  const int nW = gridDim.x * 8;

  for (int tile = waveId; tile < EE / 16; tile += nW) {
    const int e0 = tile * 16;
    if (lane < 16) {
      int s = ei[e0 + lane];
      int d = ei[EE + e0 + lane];
      miw[lane] = s;
      mfw[lane]      = x[s * 3 + 0] - x[d * 3 + 0];
      mfw[16 + lane] = x[s * 3 + 1] - x[d * 3 + 1];
      mfw[32 + lane] = x[s * 3 + 2] - x[d * 3 + 2];
    }

    bf16x8 af2[4];
#pragma unroll
    for (int kk = 0; kk < 4; ++kk)
      af2[kk] = *(const bf16x8*)&msg[(long)(e0 + cl) * DM + kk * 32 + kg * 8];

    f32x4 accx[8];
#pragma unroll
    for (int b = 0; b < 8; ++b) {
      accx[b] = (f32x4){bx1v[b], bx1v[b], bx1v[b], bx1v[b]};
#pragma unroll
      for (int kk = 0; kk < 4; ++kk) {
        int byte = ((b * 16 + cl) * 256 + kk * 64 + kg * 16) ^ ((cl & 7) << 4);
        bf16x8 bfr = *(bf16x8*)((char*)Wx1T + byte);
        accx[b] = __builtin_amdgcn_mfma_f32_16x16x32_bf16(af2[kk], bfr, accx[b], 0, 0, 0);
      }
    }

    float s0 = 0.f, s1 = 0.f, s2 = 0.f, s3 = 0.f;
#pragma unroll
    for (int b = 0; b < 8; ++b) {
      s0 += silu_f(accx[b][0]) * wxr[b];
      s1 += silu_f(accx[b][1]) * wxr[b];
      s2 += silu_f(accx[b][2]) * wxr[b];
      s3 += silu_f(accx[b][3]) * wxr[b];
    }
#pragma unroll
    for (int off = 1; off < 16; off <<= 1) {
      s0 += __shfl_xor(s0, off, 64);
      s1 += __shfl_xor(s1, off, 64);
      s2 += __shfl_xor(s2, off, 64);
      s3 += __shfl_xor(s3, off, 64);
    }

    const int rbase = kg * 4;
    if (cl < 12) {
      int r = cl / 3;
      int c = cl - 3 * r;
      float sv = (r == 0) ? s0 : ((r == 1) ? s1 : ((r == 2) ? s2 : s3));
      int row = rbase + r;
      float wgt = sv + bx2s;
      int s = miw[row];
      float dcomp = mfw[c * 16 + row];
      atomicAdd(&crd[(long)s * 3 + c], dcomp * wgt);
    }
  }
}

// --- FUSED edge kernel (fallback, verified 555 us) ---
__global__ __launch_bounds__(512, 2)
void edge_kernel(const float* __restrict__ u, const float* __restrict__ w,
                 const float* __restrict__ x, const float* __restrict__ ea,
                 const float* __restrict__ We1, const float* __restrict__ be1,
                 const float* __restrict__ We2, const float* __restrict__ be2,
                 const float* __restrict__ Wx1, const float* __restrict__ bx1,
                 const float* __restrict__ Wx2, const float* __restrict__ bx2,
                 const int* __restrict__ ei,
                 float* __restrict__ agg, float* __restrict__ crd)
{
  __shared__ unsigned short We2T[DM * DM];
  __shared__ unsigned short Wx1T[DM * DM];
  __shared__ unsigned short o1s[8][16 * DM];
  __shared__ float mfs[8][64];
  __shared__ float eas[8][256];
  __shared__ int   mis[8][32];

  const int tid = threadIdx.x;
  for (int idx = tid; idx < DM * DM; idx += 512) {
    int k = idx >> 7, n = idx & 127;
    int byte = (n * 256 + k * 2) ^ ((n & 7) << 4);
    *(unsigned short*)((char*)We2T + byte) = bf16rne(We2[idx]);
    *(unsigned short*)((char*)Wx1T + byte) = bf16rne(Wx1[idx]);
  }
  __syncthreads();

  const int lane = tid & 63;
  const int wv = tid >> 6;
  const int cl = lane & 15;
  const int kg = lane >> 4;
  const int c0 = lane * 2;
  unsigned short* o1 = o1s[wv];
  float* mfw = mfs[wv];
  float* eaw = eas[wv];
  int* miw = mis[wv];

  float wr[17][2];
#pragma unroll
  for (int t = 0; t < 17; ++t) {
    wr[t][0] = We1[(2 * DH + t) * DM + c0];
    wr[t][1] = We1[(2 * DH + t) * DM + c0 + 1];
  }
  const float be1a = be1[c0], be1b = be1[c0 + 1];
  float be2v[8], bx1v[8], wxr[8];
#pragma unroll
  for (int b = 0; b < 8; ++b) {
    be2v[b] = be2[b * 16 + cl];
    bx1v[b] = bx1[b * 16 + cl];
    wxr[b] = Wx2[b * 16 + cl];
  }
  const float bx2s = bx2[0];

  const int waveId = blockIdx.x * 8 + wv;
  const int nW = gridDim.x * 8;

  for (int tile = waveId; tile < EE / 16; tile += nW) {
    const int e0 = tile * 16;
    if (lane < 16) {
      int s = ei[e0 + lane];
      int d = ei[EE + e0 + lane];
      miw[lane] = s;
      miw[16 + lane] = d;
      float dx = x[s * 3 + 0] - x[d * 3 + 0];
      float dy = x[s * 3 + 1] - x[d * 3 + 1];
      float dz = x[s * 3 + 2] - x[d * 3 + 2];
      mfw[lane] = dx * dx + dy * dy + dz * dz;
      mfw[16 + lane] = dx;
      mfw[32 + lane] = dy;
      mfw[48 + lane] = dz;
    }
    ((float4*)eaw)[lane] = ((const float4*)(ea + (long)e0 * DE))[lane];

#pragma unroll
    for (int e = 0; e < 16; ++e) {
      int s = miw[e], d = miw[16 + e];
      float2 uu = *(const float2*)&u[(long)s * DM + c0];
      float2 ww = *(const float2*)&w[(long)d * DM + c0];
      float sq = mfw[e];
      float z0 = uu.x + ww.x + be1a + sq * wr[0][0];
      float z1 = uu.y + ww.y + be1b + sq * wr[0][1];
#pragma unroll
      for (int g = 0; g < 4; ++g) {
        float4 ev = *(const float4*)&eaw[e * 16 + 4 * g];
        z0 += ev.x * wr[1 + 4 * g][0]; z1 += ev.x * wr[1 + 4 * g][1];
        z0 += ev.y * wr[2 + 4 * g][0]; z1 += ev.y * wr[2 + 4 * g][1];
        z0 += ev.z * wr[3 + 4 * g][0]; z1 += ev.z * wr[3 + 4 * g][1];
        z0 += ev.w * wr[4 + 4 * g][0]; z1 += ev.w * wr[4 + 4 * g][1];
      }
      unsigned pk = ((unsigned)bf16rne(silu_f(z1)) << 16) | bf16rne(silu_f(z0));
      int byte = (e * 256 + c0 * 2) ^ ((e & 7) << 4);
      *(unsigned*)((char*)o1 + byte) = pk;
    }

    bf16x8 af[4];
#pragma unroll
    for (int kk = 0; kk < 4; ++kk) {
      int byte = (cl * 256 + kk * 64 + kg * 16) ^ ((cl & 7) << 4);
      af[kk] = *(bf16x8*)((char*)o1 + byte);
    }
    f32x4 acc[8];
#pragma unroll
    for (int b = 0; b < 8; ++b) {
      acc[b] = (f32x4){be2v[b], be2v[b], be2v[b], be2v[b]};
#pragma unroll
      for (int kk = 0; kk < 4; ++kk) {
        int byte = ((b * 16 + cl) * 256 + kk * 64 + kg * 16) ^ ((cl & 7) << 4);
        bf16x8 bfr = *(bf16x8*)((char*)We2T + byte);
        acc[b] = __builtin_amdgcn_mfma_f32_16x16x32_bf16(af[kk], bfr, acc[b], 0, 0, 0);
      }
    }

    const int rbase = kg * 4;
#pragma unroll
    for (int b = 0; b < 8; ++b) {
      int col = b * 16 + cl;
#pragma unroll
      for (int r = 0; r < 4; ++r) {
        int row = rbase + r;
        float m = silu_f(acc[b][r]);
        atomicAdd(&agg[(long)miw[16 + row] * DM + col], m);
        int byte = (row * 256 + col * 2) ^ ((row & 7) << 4);
        *(unsigned short*)((char*)o1 + byte) = bf16rne(m);
      }
    }

    bf16x8 af2[4];
#pragma unroll
    for (int kk = 0; kk < 4; ++kk) {
      int byte = (cl * 256 + kk * 64 + kg * 16) ^ ((cl & 7) << 4);
      af2[kk] = *(bf16x8*)((char*)o1 + byte);
    }
    f32x4 accx[8];
#pragma unroll
    for (int b = 0; b < 8; ++b) {
      accx[b] = (f32x4){bx1v[b], bx1v[b], bx1v[b], bx1v[b]};
#pragma unroll
      for (int kk = 0; kk < 4; ++kk) {
        int byte = ((b * 16 + cl) * 256 + kk * 64 + kg * 16) ^ ((cl & 7) << 4);
        bf16x8 bfr = *(bf16x8*)((char*)Wx1T + byte);
        accx[b] = __builtin_amdgcn_mfma_f32_16x16x32_bf16(af2[kk], bfr, accx[b], 0, 0, 0);
      }
    }

    float s0 = 0.f, s1 = 0.f, s2 = 0.f, s3 = 0.f;
#pragma unroll
    for (int b = 0; b < 8; ++b) {
      s0 += silu_f(accx[b][0]) * wxr[b];
      s1 += silu_f(accx[b][1]) * wxr[b];
      s2 += silu_f(accx[b][2]) * wxr[b];
      s3 += silu_f(accx[b][3]) * wxr[b];
    }
#pragma unroll
    for (int off = 1; off < 16; off <<= 1) {
      s0 += __shfl_xor(s0, off, 64);
      s1 += __shfl_xor(s1, off, 64);
      s2 += __shfl_xor(s2, off, 64);
      s3 += __shfl_xor(s3, off, 64);
    }

    if (cl < 12) {
      int r = cl / 3;
      int c = cl - 3 * r;
      float sv = (r == 0) ? s0 : ((r == 1) ? s1 : ((r == 2) ? s2 : s3));
      int row = rbase + r;
      float wgt = sv + bx2s;
      int s = miw[row];
      float dcomp = mfw[16 + c * 16 + row];
      atomicAdd(&crd[(long)s * 3 + c], dcomp * wgt);
    }
  }
}

// --- node update layer 1 via MFMA ---
__global__ __launch_bounds__(256, 2)
void upd1_mfma(const float* __restrict__ h, const float* __restrict__ agg,
               const float* __restrict__ cnt, const unsigned short* __restrict__ Wh1T,
               const float* __restrict__ bh1, unsigned short* __restrict__ t)
{
  __shared__ unsigned short B1[DM * 256];
  const int tid = threadIdx.x;
  for (int c = tid; c < 4096; c += 256) {
    int n = c >> 5, ck = c & 31;
    int sb = (n * 512 + ck * 16) ^ ((n & 7) << 4);
    *(bf16x8*)((char*)B1 + sb) = ((const bf16x8*)Wh1T)[c];
  }
  __syncthreads();
  const int lane = tid & 63, wv = tid >> 6;
  const int cl = lane & 15, kg = lane >> 4;
  float bh1v[8];
#pragma unroll
  for (int b = 0; b < 8; ++b) bh1v[b] = bh1[b * 16 + cl];
  const int waveId = blockIdx.x * 4 + wv, nW = gridDim.x * 4;
  for (int tile = waveId; tile < NN / 16; tile += nW) {
    const long rbase = (long)tile * 16;
    const float inv = __fdividef(1.0f, fmaxf(cnt[rbase + cl], 1.0f));
    bf16x8 af[8];
#pragma unroll
    for (int kk = 0; kk < 4; ++kk) {
      const float* hp = &h[(rbase + cl) * DH + kk * 32 + kg * 8];
      float4 a0 = *(const float4*)hp;
      float4 a1 = *(const float4*)(hp + 4);
      bf16x8 v;
      v[0] = (short)bf16rne(a0.x); v[1] = (short)bf16rne(a0.y);
      v[2] = (short)bf16rne(a0.z); v[3] = (short)bf16rne(a0.w);
      v[4] = (short)bf16rne(a1.x); v[5] = (short)bf16rne(a1.y);
      v[6] = (short)bf16rne(a1.z); v[7] = (short)bf16rne(a1.w);
      af[kk] = v;
    }
#pragma unroll
    for (int kk = 0; kk < 4; ++kk) {
      const float* ap = &agg[(rbase + cl) * DM + kk * 32 + kg * 8];
      float4 a0 = *(const float4*)ap;
      float4 a1 = *(const float4*)(ap + 4);
      bf16x8 v;
      v[0] = (short)bf16rne(a0.x * inv); v[1] = (short)bf16rne(a0.y * inv);
      v[2] = (short)bf16rne(a0.z * inv); v[3] = (short)bf16rne(a0.w * inv);
      v[4] = (short)bf16rne(a1.x * inv); v[5] = (short)bf16rne(a1.y * inv);
      v[6] = (short)bf16rne(a1.z * inv); v[7] = (short)bf16rne(a1.w * inv);
      af[4 + kk] = v;
    }
#pragma unroll
    for (int b = 0; b < 8; ++b) {
      f32x4 acc = (f32x4){bh1v[b], bh1v[b], bh1v[b], bh1v[b]};
#pragma unroll
      for (int kk = 0; kk < 8; ++kk) {
        int byte = ((b * 16 + cl) * 512 + kk * 64 + kg * 16) ^ ((cl & 7) << 4);
        acc = __builtin_amdgcn_mfma_f32_16x16x32_bf16(af[kk], *(bf16x8*)((char*)B1 + byte), acc, 0, 0, 0);
      }
      int col = b * 16 + cl;
#pragma unroll
      for (int r = 0; r < 4; ++r) {
        long row = rbase + kg * 4 + r;
        t[row * DM + col] = bf16rne(silu_f(acc[r]));
      }
    }
  }
}

// --- node update layer 2 via MFMA + residual + layernorm ---
__global__ __launch_bounds__(256, 2)
void upd2_mfma(const unsigned short* __restrict__ t, const float* __restrict__ h,
               const unsigned short* __restrict__ Wh2T, const float* __restrict__ bh2,
               const float* __restrict__ lng, const float* __restrict__ lnb,
               float* __restrict__ out)
{
  __shared__ unsigned short B2[DM * DM];
  const int tid = threadIdx.x;
  for (int c = tid; c < 2048; c += 256) {
    int n = c >> 4, ck = c & 15;
    int sb = (n * 256 + ck * 16) ^ ((n & 7) << 4);
    *(bf16x8*)((char*)B2 + sb) = ((const bf16x8*)Wh2T)[c];
  }
  __syncthreads();
  const int lane = tid & 63, wv = tid >> 6;
  const int cl = lane & 15, kg = lane >> 4;
  float bh2v[8], gv[8], qv[8];
#pragma unroll
  for (int b = 0; b < 8; ++b) {
    bh2v[b] = bh2[b * 16 + cl];
    gv[b] = lng[b * 16 + cl];
    qv[b] = lnb[b * 16 + cl];
  }
  const int waveId = blockIdx.x * 4 + wv, nW = gridDim.x * 4;
  for (int tile = waveId; tile < NN / 16; tile += nW) {
    const long rbase = (long)tile * 16;
    bf16x8 af[4];
#pragma unroll
    for (int kk = 0; kk < 4; ++kk)
      af[kk] = *(const bf16x8*)&t[(rbase + cl) * DM + kk * 32 + kg * 8];
    float pre[8][4];
#pragma unroll
    for (int b = 0; b < 8; ++b) {
      f32x4 acc = (f32x4){bh2v[b], bh2v[b], bh2v[b], bh2v[b]};
#pragma unroll
      for (int kk = 0; kk < 4; ++kk) {
        int byte = ((b * 16 + cl) * 256 + kk * 64 + kg * 16) ^ ((cl & 7) << 4);
        acc = __builtin_amdgcn_mfma_f32_16x16x32_bf16(af[kk], *(bf16x8*)((char*)B2 + byte), acc, 0, 0, 0);
      }
      int col = b * 16 + cl;
#pragma unroll
      for (int r = 0; r < 4; ++r)
        pre[b][r] = acc[r] + h[(rbase + kg * 4 + r) * DH + col];
    }
#pragma unroll
    for (int r = 0; r < 4; ++r) {
      float s = 0.f, q = 0.f;
#pragma unroll
      for (int b = 0; b < 8; ++b) { s += pre[b][r]; q += pre[b][r] * pre[b][r]; }
#pragma unroll
      for (int off = 1; off < 16; off <<= 1) {
        s += __shfl_xor(s, off, 64);
        q += __shfl_xor(q, off, 64);
      }
      float mean = s * (1.0f / 128.0f);
      float var = q * (1.0f / 128.0f) - mean * mean;
      float rs = rsqrtf(var + 1e-5f);
      long row = rbase + kg * 4 + r;
#pragma unroll
      for (int b = 0; b < 8; ++b) {
        out[row * DM + b * 16 + cl] = (pre[b][r] - mean) * rs * gv[b] + qv[b];
      }
    }
  }
}

// --- x output ---
__global__ __launch_bounds__(256)
void xout_kernel(const float* __restrict__ x, const float* __restrict__ crd,
                 const float* __restrict__ cnt, float* __restrict__ out)
{
  int i = blockIdx.x * 256 + threadIdx.x;
  if (i < NN * 3) {
    int n = i / 3;
    float cv = fmaxf(cnt[n], 1.0f);
    out[i] = x[i] + crd[i] * __fdividef(1.0f, cv);
  }
}

extern "C" void kernel_launch(void* const* d_in, const int* in_sizes, int n_in,
                              void* d_out, int out_size, void* d_ws, size_t ws_size,
                              hipStream_t stream)
{
  (void)in_sizes; (void)n_in; (void)out_size;
  const float* h   = (const float*)d_in[0];
  const float* x   = (const float*)d_in[1];
  const float* ea  = (const float*)d_in[2];
  const float* We1 = (const float*)d_in[3];
  const float* be1 = (const float*)d_in[4];
  const float* We2 = (const float*)d_in[5];
  const float* be2 = (const float*)d_in[6];
  const float* Wh1 = (const float*)d_in[7];
  const float* bh1 = (const float*)d_in[8];
  const float* Wh2 = (const float*)d_in[9];
  const float* bh2 = (const float*)d_in[10];
  const float* Wx1 = (const float*)d_in[11];
  const float* bx1 = (const float*)d_in[12];
  const float* Wx2 = (const float*)d_in[13];
  const float* bx2 = (const float*)d_in[14];
  const float* lng = (const float*)d_in[15];
  const float* lnb = (const float*)d_in[16];
  const int*   ei  = (const int*)d_in[17];
  float* out = (float*)d_out;
  float* ws  = (float*)d_ws;

  float* u   = ws;                 // N*128 fp32
  float* w   = ws + 6400000;       // N*128 fp32
  float* agg = ws + 12800000;      // N*128 fp32
  float* cnt = ws + 19200000;      // N
  float* crd = ws + 19250000;      // N*3
  unsigned short* WeaT = (unsigned short*)(ws + 19400000);  // 128*128
  unsigned short* WebT = WeaT + 16384;
  unsigned short* Wh1T = WebT + 16384;                      // 128*256
  unsigned short* Wh2T = Wh1T + 32768;                      // 128*128
  unsigned short* msg  = (unsigned short*)(ws + 19440960);  // E*128 bf16
  unsigned short* tbf  = (unsigned short*)w;                // reuse w after edge

  // split path needs msg region: (19440960 + 51200000) floats
  const bool use_split = ws_size >= (size_t)(19440960 + 51200000) * 4;

  hipMemsetAsync(agg, 0, (6400000 + 50000 + 150000) * sizeof(float), stream);

  prep_wt_kernel<<<128, 256, 0, stream>>>(We1, Wh1, Wh2, WeaT, WebT, Wh1T, Wh2T);
  node_pre_mfma<<<782, 256, 0, stream>>>(h, WeaT, WebT, u, w);
  count_kernel<<<(EE + 255) / 256, 256, 0, stream>>>(ei, cnt);
  if (use_split) {
    edge_msg_kernel<<<512, 512, 0, stream>>>(u, w, x, ea, We1, be1, We2, be2,
                                             ei, agg, msg);
    edge_coord_kernel<<<512, 512, 0, stream>>>(msg, x, Wx1, bx1, Wx2, bx2, ei, crd);
  } else {
    edge_kernel<<<256, 512, 0, stream>>>(u, w, x, ea, We1, be1, We2, be2,
                                         Wx1, bx1, Wx2, bx2, ei, agg, crd);
  }
  upd1_mfma<<<782, 256, 0, stream>>>(h, agg, cnt, Wh1T, bh1, tbf);
  upd2_mfma<<<782, 256, 0, stream>>>(tbf, h, Wh2T, bh2, lng, lnb, out);
  xout_kernel<<<(NN * 3 + 255) / 256, 256, 0, stream>>>(x, crd, cnt, out + 6400000);
}